// Round 3
// baseline (2046.208 us; speedup 1.0000x reference)
//
#include <hip/hip_runtime.h>
#include <hip/hip_bf16.h>

typedef __hip_bfloat16 bf16_t;

#define LQ 512
#define LK 4096
#define BATCH 4
#define DMODEL 512
#define NHEAD 8
#define HEADDIM 64
#define DFF 2048
#define LN_EPS 1e-5f

// ---------- helpers ----------
__device__ inline float tofl(float x) { return x; }
__device__ inline float tofl(bf16_t x) { return __bfloat162float(x); }
__device__ inline void stfl(float* p, float v) { *p = v; }
__device__ inline void stfl(bf16_t* p, float v) { *p = __float2bfloat16(v); }

// ---------- LayerNorm over 512 cols, one block (256 thr) per row ----------
template <typename TIN, typename TOUT>
__global__ void ln_kernel(const TIN* __restrict__ in, const float* __restrict__ w,
                          const float* __restrict__ b, TOUT* __restrict__ out) {
    __shared__ float red[256];
    const int row = blockIdx.x;
    const int tid = threadIdx.x;
    const TIN* x = in + (size_t)row * DMODEL;
    float v0 = tofl(x[tid]);
    float v1 = tofl(x[tid + 256]);

    red[tid] = v0 + v1;
    __syncthreads();
    for (int s = 128; s > 0; s >>= 1) { if (tid < s) red[tid] += red[tid + s]; __syncthreads(); }
    float mu = red[0] * (1.0f / DMODEL);
    __syncthreads();

    float d0 = v0 - mu, d1 = v1 - mu;
    red[tid] = d0 * d0 + d1 * d1;
    __syncthreads();
    for (int s = 128; s > 0; s >>= 1) { if (tid < s) red[tid] += red[tid + s]; __syncthreads(); }
    float inv = rsqrtf(red[0] * (1.0f / DMODEL) + LN_EPS);

    TOUT* o = out + (size_t)row * DMODEL;
    stfl(&o[tid],       d0 * inv * w[tid]       + b[tid]);
    stfl(&o[tid + 256], d1 * inv * w[tid + 256] + b[tid + 256]);
}

// ---------- GEMM: C[M,N] = A[M,K] * B[N,K]^T + bias[N] (+resid) (+relu) ----------
// 64x64 tile, BK=16, 256 threads, 4x4/thread.
#define BM 64
#define BN 64
#define BKK 16
template <typename TA, typename TC, bool RELU, bool RESID>
__global__ void gemm_bt(const TA* __restrict__ A, const float* __restrict__ B,
                        const float* __restrict__ bias, const float* __restrict__ resid,
                        TC* __restrict__ C, int M, int N, int K) {
    __shared__ float As[BKK][BM];
    __shared__ float Bs[BKK][BN];
    const int tid = threadIdx.x;
    const int tx = tid & 15, ty = tid >> 4;
    const int n0 = blockIdx.x * BN;
    const int m0 = blockIdx.y * BM;
    float acc[4][4] = {};

    for (int k0 = 0; k0 < K; k0 += BKK) {
#pragma unroll
        for (int i = 0; i < 4; i++) {
            int idx = i * 256 + tid;
            int r = idx >> 4, c = idx & 15;
            As[c][r] = tofl(A[(size_t)(m0 + r) * K + k0 + c]);
        }
#pragma unroll
        for (int i = 0; i < 4; i++) {
            int idx = i * 256 + tid;
            int n = idx >> 4, c = idx & 15;
            Bs[c][n] = B[(size_t)(n0 + n) * K + k0 + c];
        }
        __syncthreads();
#pragma unroll
        for (int kk = 0; kk < BKK; kk++) {
            float a[4], bv[4];
#pragma unroll
            for (int i = 0; i < 4; i++) a[i] = As[kk][ty * 4 + i];
#pragma unroll
            for (int j = 0; j < 4; j++) bv[j] = Bs[kk][tx * 4 + j];
#pragma unroll
            for (int i = 0; i < 4; i++)
#pragma unroll
                for (int j = 0; j < 4; j++) acc[i][j] += a[i] * bv[j];
        }
        __syncthreads();
    }

#pragma unroll
    for (int i = 0; i < 4; i++) {
        int r = m0 + ty * 4 + i;
#pragma unroll
        for (int j = 0; j < 4; j++) {
            int c = n0 + tx * 4 + j;
            float val = acc[i][j] + bias[c];
            if (RESID) val += resid[(size_t)r * N + c];
            if (RELU) val = fmaxf(val, 0.0f);
            stfl(&C[(size_t)r * N + c], val);
        }
    }
}

// ---------- Fused windowed attention ----------
// grid (LQ, BATCH), 256 threads. q fp32, k/v bf16, rows laid out (l,b) -> l*BATCH+b.
__global__ void attn_kernel(const float* __restrict__ q, const bf16_t* __restrict__ k,
                            const bf16_t* __restrict__ v, float* __restrict__ ctx,
                            float* __restrict__ attn_out) {
    const int qi = blockIdx.x;
    const int b  = blockIdx.y;
    const int tid = threadIdx.x;

    // adaptive mask window: start = qi*8, end = start+827, clamped to [3268,4096)
    int start = qi * 8;
    int end = start + 827;
    if (end > LK - 1) { start -= (end - (LK - 1)); if (start < 0) start = 0; end = LK; }
    const int W = end - start;  // 827 or 828

    __shared__ float qv[DMODEL];
    __shared__ float sc[828];
    __shared__ float accp[828];
    __shared__ float red[256];
    __shared__ float cpart[4][64];

    const size_t qrow = ((size_t)qi * BATCH + b) * DMODEL;
    const float scale = 0.125f;  // 1/sqrt(64)
    for (int i = tid; i < DMODEL; i += 256) qv[i] = q[qrow + i] * scale;
    for (int i = tid; i < W; i += 256) accp[i] = 0.0f;
    __syncthreads();

    for (int h = 0; h < NHEAD; h++) {
        // scores
        for (int i = tid; i < W; i += 256) {
            int kk = start + i;
            const __hip_bfloat162* k2 = reinterpret_cast<const __hip_bfloat162*>(
                k + ((size_t)kk * BATCH + b) * DMODEL + h * HEADDIM);
            float dot = 0.0f;
#pragma unroll
            for (int d2 = 0; d2 < 32; d2++) {
                float2 kf = __bfloat1622float2(k2[d2]);
                dot += qv[h * 64 + d2 * 2 + 0] * kf.x;
                dot += qv[h * 64 + d2 * 2 + 1] * kf.y;
            }
            sc[i] = dot;
        }
        __syncthreads();
        // max
        float mx = -1e30f;
        for (int i = tid; i < W; i += 256) mx = fmaxf(mx, sc[i]);
        red[tid] = mx; __syncthreads();
        for (int s = 128; s > 0; s >>= 1) { if (tid < s) red[tid] = fmaxf(red[tid], red[tid + s]); __syncthreads(); }
        mx = red[0]; __syncthreads();
        // exp + sum
        float sm = 0.0f;
        for (int i = tid; i < W; i += 256) { float e = __expf(sc[i] - mx); sc[i] = e; sm += e; }
        red[tid] = sm; __syncthreads();
        for (int s = 128; s > 0; s >>= 1) { if (tid < s) red[tid] += red[tid + s]; __syncthreads(); }
        float inv = 1.0f / red[0]; __syncthreads();
        for (int i = tid; i < W; i += 256) { float p = sc[i] * inv; sc[i] = p; accp[i] += p * 0.125f; }
        __syncthreads();
        // ctx: 4 groups x 64 dims
        const int g = tid >> 6;
        const int dd = tid & 63;
        float cs = 0.0f;
        for (int i = g; i < W; i += 4) {
            int kk = start + i;
            cs += sc[i] * __bfloat162float(v[((size_t)kk * BATCH + b) * DMODEL + h * HEADDIM + dd]);
        }
        cpart[g][dd] = cs; __syncthreads();
        if (tid < 64) {
            ctx[qrow + h * 64 + tid] = cpart[0][tid] + cpart[1][tid] + cpart[2][tid] + cpart[3][tid];
        }
        __syncthreads();
    }

    // attn_weights [B, LQ, LK]
    const size_t arow = ((size_t)b * LQ + qi) * (size_t)LK;
    for (int col = tid; col < LK; col += 256) {
        float pv = (col >= start && col < end) ? accp[col - start] : 0.0f;
        attn_out[arow + col] = pv;
    }
}

extern "C" void kernel_launch(void* const* d_in, const int* in_sizes, int n_in,
                              void* d_out, int out_size, void* d_ws, size_t ws_size,
                              hipStream_t stream) {
    const float* tgt    = (const float*)d_in[0];
    const float* memory = (const float*)d_in[1];
    const float* Wq = (const float*)d_in[2];
    const float* bq = (const float*)d_in[3];
    const float* Wk = (const float*)d_in[4];
    const float* bk = (const float*)d_in[5];
    const float* Wv = (const float*)d_in[6];
    const float* bv = (const float*)d_in[7];
    const float* Wo = (const float*)d_in[8];
    const float* bo = (const float*)d_in[9];
    const float* W1 = (const float*)d_in[10];
    const float* b1 = (const float*)d_in[11];
    const float* W2 = (const float*)d_in[12];
    const float* b2 = (const float*)d_in[13];
    const float* ln1w = (const float*)d_in[14];
    const float* ln1b = (const float*)d_in[15];
    const float* ln2w = (const float*)d_in[16];
    const float* ln2b = (const float*)d_in[17];
    const float* ln3w = (const float*)d_in[18];
    const float* ln3b = (const float*)d_in[19];
    const float* ln4w = (const float*)d_in[20];
    const float* ln4b = (const float*)d_in[21];

    const size_t M1 = (size_t)LQ * BATCH;      // 2048
    const size_t M2 = (size_t)LK * BATCH;      // 16384
    const size_t SZ1 = M1 * DMODEL;            // 1,048,576

    // ---- workspace layout with lifetime aliasing (total 60 MiB) ----
    // A [0,4): t, then xln     B [4,8): q, then xres    C [8,12): ctx, then x2
    // [12,28): m (bf16), then h (bf16, 8 MiB)   [28,44): k bf16   [44,60): v bf16
    char* wsb = (char*)d_ws;
    const size_t MB = 1 << 20;
    float*  t_buf   = (float*)(wsb + 0 * MB);
    float*  xln     = (float*)(wsb + 0 * MB);
    float*  q_buf   = (float*)(wsb + 4 * MB);
    float*  xres    = (float*)(wsb + 4 * MB);
    float*  ctx_buf = (float*)(wsb + 8 * MB);
    float*  x2_buf  = (float*)(wsb + 8 * MB);
    bf16_t* m_buf   = (bf16_t*)(wsb + 12 * MB);
    bf16_t* h_buf   = (bf16_t*)(wsb + 12 * MB);
    bf16_t* k_buf   = (bf16_t*)(wsb + 28 * MB);
    bf16_t* v_buf   = (bf16_t*)(wsb + 44 * MB);

    float* out_x    = (float*)d_out;
    float* out_attn = out_x + SZ1;

    // LN1 / LN2
    ln_kernel<float, float><<<dim3(M1), dim3(256), 0, stream>>>(tgt, ln1w, ln1b, t_buf);
    ln_kernel<float, bf16_t><<<dim3(M2), dim3(256), 0, stream>>>(memory, ln2w, ln2b, m_buf);

    // projections
    gemm_bt<float, float, false, false><<<dim3(DMODEL / BN, M1 / BM), dim3(256), 0, stream>>>(
        t_buf, Wq, bq, nullptr, q_buf, M1, DMODEL, DMODEL);
    gemm_bt<bf16_t, bf16_t, false, false><<<dim3(DMODEL / BN, M2 / BM), dim3(256), 0, stream>>>(
        m_buf, Wk, bk, nullptr, k_buf, M2, DMODEL, DMODEL);
    gemm_bt<bf16_t, bf16_t, false, false><<<dim3(DMODEL / BN, M2 / BM), dim3(256), 0, stream>>>(
        m_buf, Wv, bv, nullptr, v_buf, M2, DMODEL, DMODEL);

    // fused attention (q dead after this; ctx live)
    attn_kernel<<<dim3(LQ, BATCH), dim3(256), 0, stream>>>(q_buf, k_buf, v_buf, ctx_buf, out_attn);

    // out proj + residual (t!) -> xres (aliases q)
    gemm_bt<float, float, false, true><<<dim3(DMODEL / BN, M1 / BM), dim3(256), 0, stream>>>(
        ctx_buf, Wo, bo, t_buf, xres, M1, DMODEL, DMODEL);

    // LN3 -> xln (aliases t; t dead now)
    ln_kernel<float, float><<<dim3(M1), dim3(256), 0, stream>>>(xres, ln3w, ln3b, xln);

    // FF1 -> h (aliases m; m dead now)
    gemm_bt<float, bf16_t, true, false><<<dim3(DFF / BN, M1 / BM), dim3(256), 0, stream>>>(
        xln, W1, b1, nullptr, h_buf, M1, DFF, DMODEL);
    // FF2 + residual(xln) -> x2 (aliases ctx; ctx dead now)
    gemm_bt<bf16_t, float, false, true><<<dim3(DMODEL / BN, M1 / BM), dim3(256), 0, stream>>>(
        h_buf, W2, b2, xln, x2_buf, M1, DMODEL, DFF);

    // LN4 -> fp32 out
    ln_kernel<float, float><<<dim3(M1), dim3(256), 0, stream>>>(x2_buf, ln4w, ln4b, out_x);
}

// Round 4
// 820.764 us; speedup vs baseline: 2.4931x; 2.4931x over previous
//
#include <hip/hip_runtime.h>
#include <hip/hip_bf16.h>

typedef __hip_bfloat16 bf16_t;
typedef __bf16 bf16x8 __attribute__((ext_vector_type(8)));
typedef float f32x4 __attribute__((ext_vector_type(4)));

#define LQ 512
#define LK 4096
#define BATCH 4
#define DMODEL 512
#define NHEAD 8
#define HEADDIM 64
#define DFF 2048
#define LN_EPS 1e-5f

__device__ inline float tofl(float x) { return x; }
__device__ inline float tofl(bf16_t x) { return __bfloat162float(x); }
__device__ inline void stfl(float* p, float v) { *p = v; }
__device__ inline void stfl(bf16_t* p, float v) { *p = __float2bfloat16(v); }

// ---------- fp32 -> bf16 weight conversion ----------
__global__ void convw_kernel(const float* __restrict__ in, bf16_t* __restrict__ out, int n) {
    int i = (blockIdx.x * 256 + threadIdx.x) * 4;
    if (i + 3 < n) {
        float4 v = *(const float4*)(in + i);
        out[i + 0] = __float2bfloat16(v.x);
        out[i + 1] = __float2bfloat16(v.y);
        out[i + 2] = __float2bfloat16(v.z);
        out[i + 3] = __float2bfloat16(v.w);
    }
}
// 4 x [512x512] weights in one launch
__global__ void conv4_kernel(const float* __restrict__ s0, const float* __restrict__ s1,
                             const float* __restrict__ s2, const float* __restrict__ s3,
                             bf16_t* __restrict__ dst) {
    int t = blockIdx.x * 256 + threadIdx.x;      // 262144 threads
    int which = t >> 16;
    int idx = (t & 65535) * 4;
    const float* s = which == 0 ? s0 : which == 1 ? s1 : which == 2 ? s2 : s3;
    float4 v = *(const float4*)(s + idx);
    bf16_t* d = dst + (size_t)which * 262144 + idx;
    d[0] = __float2bfloat16(v.x); d[1] = __float2bfloat16(v.y);
    d[2] = __float2bfloat16(v.z); d[3] = __float2bfloat16(v.w);
}

// ---------- LayerNorm over 512 cols, one block (256 thr) per row ----------
// DUAL: write bf16 out1 + fp32 out2 (for later residual use)
template <typename TOUT, bool DUAL>
__global__ void ln_kernel(const float* __restrict__ in, const float* __restrict__ w,
                          const float* __restrict__ b, TOUT* __restrict__ out1,
                          float* __restrict__ out2) {
    __shared__ float red[256];
    const int row = blockIdx.x;
    const int tid = threadIdx.x;
    const float* x = in + (size_t)row * DMODEL;
    float v0 = x[tid];
    float v1 = x[tid + 256];

    red[tid] = v0 + v1;
    __syncthreads();
    for (int s = 128; s > 0; s >>= 1) { if (tid < s) red[tid] += red[tid + s]; __syncthreads(); }
    float mu = red[0] * (1.0f / DMODEL);
    __syncthreads();

    float d0 = v0 - mu, d1 = v1 - mu;
    red[tid] = d0 * d0 + d1 * d1;
    __syncthreads();
    for (int s = 128; s > 0; s >>= 1) { if (tid < s) red[tid] += red[tid + s]; __syncthreads(); }
    float inv = rsqrtf(red[0] * (1.0f / DMODEL) + LN_EPS);

    float r0 = d0 * inv * w[tid] + b[tid];
    float r1 = d1 * inv * w[tid + 256] + b[tid + 256];
    TOUT* o = out1 + (size_t)row * DMODEL;
    stfl(&o[tid], r0);
    stfl(&o[tid + 256], r1);
    if (DUAL) {
        float* o2 = out2 + (size_t)row * DMODEL;
        o2[tid] = r0;
        o2[tid + 256] = r1;
    }
}

// ---------- MFMA GEMM: C[M,N] = A[M,K](bf16) * B[N,K](bf16)^T + bias (+resid)(+relu) ----------
// 128x128 tile, BK=64, 256 threads (4 waves, 2x2 of 64x64), 16x16x32 MFMA.
#define GBM 128
#define GBN 128
#define GBK 64
#define PLANE 1032   // 128*8 + 8 pad elements per k-chunk plane (2064 B -> conflict-balanced)
template <typename TC, bool RELU, bool RESID>
__global__ __launch_bounds__(256) void gemm_mfma(
        const bf16_t* __restrict__ A, const bf16_t* __restrict__ B,
        const float* __restrict__ bias, const float* __restrict__ resid,
        TC* __restrict__ C, int M, int N, int K) {
    __shared__ bf16_t As[8 * PLANE];
    __shared__ bf16_t Bs[8 * PLANE];

    const int tid = threadIdx.x;
    const int lane = tid & 63;
    const int wave = tid >> 6;
    const int wy = wave >> 1, wx = wave & 1;       // wave tile: 64x64
    const int m_base = wy * 64, n_base = wx * 64;
    const int row16 = lane & 15;
    const int quad = lane >> 4;
    const int n0 = blockIdx.x * GBN;
    const int m0 = blockIdx.y * GBM;

    f32x4 acc[4][4] = {};

    for (int k0 = 0; k0 < K; k0 += GBK) {
        // stage A,B tiles: 1024 16B-transfers each; t -> (kc = t&7, r = t>>3)
#pragma unroll
        for (int it = 0; it < 4; it++) {
            int t = it * 256 + tid;
            int kc = t & 7, r = t >> 3;
            *(uint4*)&As[kc * PLANE + r * 8] =
                *(const uint4*)(A + (size_t)(m0 + r) * K + k0 + kc * 8);
        }
#pragma unroll
        for (int it = 0; it < 4; it++) {
            int t = it * 256 + tid;
            int kc = t & 7, r = t >> 3;
            *(uint4*)&Bs[kc * PLANE + r * 8] =
                *(const uint4*)(B + (size_t)(n0 + r) * K + k0 + kc * 8);
        }
        __syncthreads();
#pragma unroll
        for (int s = 0; s < 2; s++) {
            bf16x8 af[4], bf[4];
#pragma unroll
            for (int i = 0; i < 4; i++)
                af[i] = *(const bf16x8*)&As[(s * 4 + quad) * PLANE + (m_base + i * 16 + row16) * 8];
#pragma unroll
            for (int j = 0; j < 4; j++)
                bf[j] = *(const bf16x8*)&Bs[(s * 4 + quad) * PLANE + (n_base + j * 16 + row16) * 8];
#pragma unroll
            for (int i = 0; i < 4; i++)
#pragma unroll
                for (int j = 0; j < 4; j++)
                    acc[i][j] = __builtin_amdgcn_mfma_f32_16x16x32_bf16(af[i], bf[j], acc[i][j], 0, 0, 0);
        }
        __syncthreads();
    }

    // epilogue: C/D layout col = lane&15, row = quad*4 + reg  [m89]
#pragma unroll
    for (int i = 0; i < 4; i++) {
#pragma unroll
        for (int j = 0; j < 4; j++) {
            int col = n0 + n_base + j * 16 + row16;
            float bsv = bias[col];
#pragma unroll
            for (int r = 0; r < 4; r++) {
                int row = m0 + m_base + i * 16 + quad * 4 + r;
                float val = acc[i][j][r] + bsv;
                if (RESID) val += resid[(size_t)row * N + col];
                if (RELU) val = fmaxf(val, 0.0f);
                stfl(&C[(size_t)row * N + col], val);
            }
        }
    }
}

// ---------- Fused windowed attention, wave-per-head ----------
// grid (LQ, BATCH), 256 thr = 4 waves; wave w handles heads w and w+4.
__global__ __launch_bounds__(256) void attn_kernel(
        const float* __restrict__ q, const bf16_t* __restrict__ k,
        const bf16_t* __restrict__ v, bf16_t* __restrict__ ctx,
        float* __restrict__ attn_out) {
    const int qi = blockIdx.x;
    const int b  = blockIdx.y;
    const int tid = threadIdx.x;
    const int lane = tid & 63;
    const int w = tid >> 6;

    int start = qi * 8;
    int end = start + 827;
    if (end > LK - 1) { start -= (end - (LK - 1)); if (start < 0) start = 0; end = LK; }
    const int W = end - start;   // 827 or 828 (<= 832 = 13*64)

    __shared__ float qv[DMODEL];
    __shared__ float p_lds[4][832];
    __shared__ float accp[4][832];

    const size_t qrow = ((size_t)qi * BATCH + b) * DMODEL;
    for (int i = tid; i < DMODEL; i += 256) qv[i] = q[qrow + i] * 0.125f;
    {
        float* af = &accp[0][0];
        for (int i = tid; i < 4 * 832; i += 256) af[i] = 0.0f;
    }
    __syncthreads();

    for (int hh = 0; hh < 2; hh++) {
        const int h = w + hh * 4;
        const int hoff = h * HEADDIM;

        // ---- scores: 13 chunks of 64 keys, lane j -> key start + c*64 + j ----
        float s[13];
        float mx = -1e30f;
#pragma unroll
        for (int c = 0; c < 13; c++) {
            int idx = c * 64 + lane;
            float dot = -1e30f;
            if (idx < W) {
                const __hip_bfloat162* k2 = reinterpret_cast<const __hip_bfloat162*>(
                    k + ((size_t)(start + idx) * BATCH + b) * DMODEL + hoff);
                dot = 0.0f;
#pragma unroll
                for (int d2 = 0; d2 < 32; d2++) {
                    float2 kf = __bfloat1622float2(k2[d2]);
                    dot += qv[hoff + d2 * 2 + 0] * kf.x;
                    dot += qv[hoff + d2 * 2 + 1] * kf.y;
                }
            }
            s[c] = dot;
            mx = fmaxf(mx, dot);
        }
        // wave max
#pragma unroll
        for (int off = 32; off > 0; off >>= 1) mx = fmaxf(mx, __shfl_xor(mx, off, 64));
        // exp + wave sum
        float sm = 0.0f;
#pragma unroll
        for (int c = 0; c < 13; c++) { s[c] = __expf(s[c] - mx); sm += s[c]; }
#pragma unroll
        for (int off = 32; off > 0; off >>= 1) sm += __shfl_xor(sm, off, 64);
        float inv = 1.0f / sm;
        // p -> LDS, accumulate head-mean
#pragma unroll
        for (int c = 0; c < 13; c++) {
            int idx = c * 64 + lane;
            float p = s[c] * inv;
            p_lds[w][idx] = p;
            accp[w][idx] += p * 0.125f;
        }

        // ---- ctx: lane owns dim `lane`; sum over window ----
        const bf16_t* vb = v + (size_t)start * BATCH * DMODEL + (size_t)b * DMODEL + hoff + lane;
        float a0 = 0.f, a1 = 0.f, a2 = 0.f, a3 = 0.f;
        int i = 0;
        for (; i + 4 <= W; i += 4) {
            float p0 = p_lds[w][i], p1 = p_lds[w][i + 1], p2 = p_lds[w][i + 2], p3 = p_lds[w][i + 3];
            a0 += p0 * tofl(vb[(size_t)(i + 0) * BATCH * DMODEL]);
            a1 += p1 * tofl(vb[(size_t)(i + 1) * BATCH * DMODEL]);
            a2 += p2 * tofl(vb[(size_t)(i + 2) * BATCH * DMODEL]);
            a3 += p3 * tofl(vb[(size_t)(i + 3) * BATCH * DMODEL]);
        }
        for (; i < W; i++) a0 += p_lds[w][i] * tofl(vb[(size_t)i * BATCH * DMODEL]);
        ctx[qrow + hoff + lane] = __float2bfloat16(a0 + a1 + a2 + a3);
    }
    __syncthreads();

    // attn_weights [B, LQ, LK]: mean over heads = sum of 4 wave partials
    const size_t arow = ((size_t)b * LQ + qi) * (size_t)LK;
    for (int col = tid; col < LK; col += 256) {
        float pv = 0.0f;
        if (col >= start && col < end) {
            int i = col - start;
            pv = accp[0][i] + accp[1][i] + accp[2][i] + accp[3][i];
        }
        attn_out[arow + col] = pv;
    }
}

extern "C" void kernel_launch(void* const* d_in, const int* in_sizes, int n_in,
                              void* d_out, int out_size, void* d_ws, size_t ws_size,
                              hipStream_t stream) {
    const float* tgt    = (const float*)d_in[0];
    const float* memory = (const float*)d_in[1];
    const float* Wq = (const float*)d_in[2];
    const float* bq = (const float*)d_in[3];
    const float* Wk = (const float*)d_in[4];
    const float* bk = (const float*)d_in[5];
    const float* Wv = (const float*)d_in[6];
    const float* bv = (const float*)d_in[7];
    const float* Wo = (const float*)d_in[8];
    const float* bo = (const float*)d_in[9];
    const float* W1 = (const float*)d_in[10];
    const float* b1 = (const float*)d_in[11];
    const float* W2 = (const float*)d_in[12];
    const float* b2 = (const float*)d_in[13];
    const float* ln1w = (const float*)d_in[14];
    const float* ln1b = (const float*)d_in[15];
    const float* ln2w = (const float*)d_in[16];
    const float* ln2b = (const float*)d_in[17];
    const float* ln3w = (const float*)d_in[18];
    const float* ln3b = (const float*)d_in[19];
    const float* ln4w = (const float*)d_in[20];
    const float* ln4b = (const float*)d_in[21];

    const size_t M1 = (size_t)LQ * BATCH;      // 2048
    const size_t M2 = (size_t)LK * BATCH;      // 16384
    const size_t SZ1 = M1 * DMODEL;

    // ---- workspace layout (64 MiB total, lifetime-aliased) ----
    char* wsb = (char*)d_ws;
    const size_t MB = 1 << 20;
    bf16_t* m_buf   = (bf16_t*)(wsb + 0 * MB);   // [16384,512] bf16, dead after K/V proj
    bf16_t* h_buf   = (bf16_t*)(wsb + 0 * MB);   // [2048,2048] bf16 (aliases m)
    float*  xln_f   = (float*)(wsb + 8 * MB);    // [2048,512] fp32 (aliases m)
    float*  x2_buf  = (float*)(wsb + 12 * MB);   // [2048,512] fp32 (aliases m)
    bf16_t* k_buf   = (bf16_t*)(wsb + 16 * MB);  // [16384,512] bf16
    bf16_t* v_buf   = (bf16_t*)(wsb + 32 * MB);  // [16384,512] bf16
    bf16_t* t_bf    = (bf16_t*)(wsb + 48 * MB);  // [2048,512] bf16, dead after Qproj
    bf16_t* xln_bf  = (bf16_t*)(wsb + 48 * MB);  // (aliases t_bf)
    float*  t_f32   = (float*)(wsb + 50 * MB);   // [2048,512] fp32 residual
    float*  q_buf   = (float*)(wsb + 54 * MB);   // [2048,512] fp32, dead after attn
    float*  xres    = (float*)(wsb + 54 * MB);   // (aliases q)
    bf16_t* ctx_buf = (bf16_t*)(wsb + 58 * MB);  // [2048,512] bf16
    bf16_t* wqkvo   = (bf16_t*)(wsb + 60 * MB);  // 4 x [512,512] bf16
    bf16_t* wff     = (bf16_t*)(wsb + 62 * MB);  // [2048,512] bf16 (W1 then W2)

    bf16_t* Wq_bf = wqkvo;
    bf16_t* Wk_bf = wqkvo + 262144;
    bf16_t* Wv_bf = wqkvo + 2 * 262144;
    bf16_t* Wo_bf = wqkvo + 3 * 262144;

    float* out_x    = (float*)d_out;
    float* out_attn = out_x + SZ1;

    // weight conversions (attention weights)
    conv4_kernel<<<dim3(1024), dim3(256), 0, stream>>>(Wq, Wk, Wv, Wo, wqkvo);

    // LN1 (dual) / LN2
    ln_kernel<bf16_t, true><<<dim3(M1), dim3(256), 0, stream>>>(tgt, ln1w, ln1b, t_bf, t_f32);
    ln_kernel<bf16_t, false><<<dim3(M2), dim3(256), 0, stream>>>(memory, ln2w, ln2b, m_buf, nullptr);

    // projections (MFMA)
    gemm_mfma<float, false, false><<<dim3(DMODEL / GBN, M1 / GBM), dim3(256), 0, stream>>>(
        t_bf, Wq_bf, bq, nullptr, q_buf, M1, DMODEL, DMODEL);
    gemm_mfma<bf16_t, false, false><<<dim3(DMODEL / GBN, M2 / GBM), dim3(256), 0, stream>>>(
        m_buf, Wk_bf, bk, nullptr, k_buf, M2, DMODEL, DMODEL);
    gemm_mfma<bf16_t, false, false><<<dim3(DMODEL / GBN, M2 / GBM), dim3(256), 0, stream>>>(
        m_buf, Wv_bf, bv, nullptr, v_buf, M2, DMODEL, DMODEL);

    // fused attention
    attn_kernel<<<dim3(LQ, BATCH), dim3(256), 0, stream>>>(q_buf, k_buf, v_buf, ctx_buf, out_attn);

    // out proj + residual(t)
    gemm_mfma<float, false, true><<<dim3(DMODEL / GBN, M1 / GBM), dim3(256), 0, stream>>>(
        ctx_buf, Wo_bf, bo, t_f32, xres, M1, DMODEL, DMODEL);

    // LN3 (dual)
    ln_kernel<bf16_t, true><<<dim3(M1), dim3(256), 0, stream>>>(xres, ln3w, ln3b, xln_bf, xln_f);

    // FF1 (relu) -- convert W1 first
    convw_kernel<<<dim3(1024), dim3(256), 0, stream>>>(W1, wff, DFF * DMODEL);
    gemm_mfma<bf16_t, true, false><<<dim3(DFF / GBN, M1 / GBM), dim3(256), 0, stream>>>(
        xln_bf, wff, b1, nullptr, h_buf, M1, DFF, DMODEL);

    // FF2 + residual(xln) -- convert W2 (reuses wff region)
    convw_kernel<<<dim3(1024), dim3(256), 0, stream>>>(W2, wff, DMODEL * DFF);
    gemm_mfma<float, false, true><<<dim3(DMODEL / GBN, M1 / GBM), dim3(256), 0, stream>>>(
        h_buf, wff, b2, xln_f, x2_buf, M1, DMODEL, DFF);

    // LN4 -> fp32 out
    ln_kernel<float, false><<<dim3(M1), dim3(256), 0, stream>>>(x2_buf, ln4w, ln4b, out_x, nullptr);
}

// Round 5
// 602.872 us; speedup vs baseline: 3.3941x; 1.3614x over previous
//
#include <hip/hip_runtime.h>
#include <hip/hip_bf16.h>

typedef __hip_bfloat16 bf16_t;
typedef __bf16 bf16x8 __attribute__((ext_vector_type(8)));
typedef __bf16 bf16x4v __attribute__((ext_vector_type(4)));
typedef __bf16 bf16x2v __attribute__((ext_vector_type(2)));
typedef float f32x4 __attribute__((ext_vector_type(4)));

#define LQ 512
#define LK 4096
#define BATCH 4
#define DMODEL 512
#define NHEAD 8
#define HEADDIM 64
#define DFF 2048
#define LN_EPS 1e-5f

__device__ inline float tofl(float x) { return x; }
__device__ inline float tofl(bf16_t x) { return __bfloat162float(x); }
__device__ inline void stfl(float* p, float v) { *p = v; }
__device__ inline void stfl(bf16_t* p, float v) { *p = __float2bfloat16(v); }

// ---------- fp32 -> bf16 weight conversion ----------
__global__ void convw_kernel(const float* __restrict__ in, bf16_t* __restrict__ out, int n) {
    int i = (blockIdx.x * 256 + threadIdx.x) * 4;
    if (i + 3 < n) {
        float4 v = *(const float4*)(in + i);
        out[i + 0] = __float2bfloat16(v.x);
        out[i + 1] = __float2bfloat16(v.y);
        out[i + 2] = __float2bfloat16(v.z);
        out[i + 3] = __float2bfloat16(v.w);
    }
}
__global__ void conv4_kernel(const float* __restrict__ s0, const float* __restrict__ s1,
                             const float* __restrict__ s2, const float* __restrict__ s3,
                             bf16_t* __restrict__ dst) {
    int t = blockIdx.x * 256 + threadIdx.x;
    int which = t >> 16;
    int idx = (t & 65535) * 4;
    const float* s = which == 0 ? s0 : which == 1 ? s1 : which == 2 ? s2 : s3;
    float4 v = *(const float4*)(s + idx);
    bf16_t* d = dst + (size_t)which * 262144 + idx;
    d[0] = __float2bfloat16(v.x); d[1] = __float2bfloat16(v.y);
    d[2] = __float2bfloat16(v.z); d[3] = __float2bfloat16(v.w);
}

// ---------- LayerNorm ----------
template <typename TOUT, bool DUAL>
__global__ void ln_kernel(const float* __restrict__ in, const float* __restrict__ w,
                          const float* __restrict__ b, TOUT* __restrict__ out1,
                          float* __restrict__ out2) {
    __shared__ float red[256];
    const int row = blockIdx.x;
    const int tid = threadIdx.x;
    const float* x = in + (size_t)row * DMODEL;
    float v0 = x[tid];
    float v1 = x[tid + 256];

    red[tid] = v0 + v1;
    __syncthreads();
    for (int s = 128; s > 0; s >>= 1) { if (tid < s) red[tid] += red[tid + s]; __syncthreads(); }
    float mu = red[0] * (1.0f / DMODEL);
    __syncthreads();

    float d0 = v0 - mu, d1 = v1 - mu;
    red[tid] = d0 * d0 + d1 * d1;
    __syncthreads();
    for (int s = 128; s > 0; s >>= 1) { if (tid < s) red[tid] += red[tid + s]; __syncthreads(); }
    float inv = rsqrtf(red[0] * (1.0f / DMODEL) + LN_EPS);

    float r0 = d0 * inv * w[tid] + b[tid];
    float r1 = d1 * inv * w[tid + 256] + b[tid + 256];
    TOUT* o = out1 + (size_t)row * DMODEL;
    stfl(&o[tid], r0);
    stfl(&o[tid + 256], r1);
    if (DUAL) {
        float* o2 = out2 + (size_t)row * DMODEL;
        o2[tid] = r0;
        o2[tid + 256] = r1;
    }
}

// ---------- MFMA GEMM (unchanged from R4) ----------
#define GBM 128
#define GBN 128
#define GBK 64
#define PLANE 1032
template <typename TC, bool RELU, bool RESID>
__global__ __launch_bounds__(256) void gemm_mfma(
        const bf16_t* __restrict__ A, const bf16_t* __restrict__ B,
        const float* __restrict__ bias, const float* __restrict__ resid,
        TC* __restrict__ C, int M, int N, int K) {
    __shared__ bf16_t As[8 * PLANE];
    __shared__ bf16_t Bs[8 * PLANE];

    const int tid = threadIdx.x;
    const int lane = tid & 63;
    const int wave = tid >> 6;
    const int wy = wave >> 1, wx = wave & 1;
    const int m_base = wy * 64, n_base = wx * 64;
    const int row16 = lane & 15;
    const int quad = lane >> 4;
    const int n0 = blockIdx.x * GBN;
    const int m0 = blockIdx.y * GBM;

    f32x4 acc[4][4] = {};

    for (int k0 = 0; k0 < K; k0 += GBK) {
#pragma unroll
        for (int it = 0; it < 4; it++) {
            int t = it * 256 + tid;
            int kc = t & 7, r = t >> 3;
            *(uint4*)&As[kc * PLANE + r * 8] =
                *(const uint4*)(A + (size_t)(m0 + r) * K + k0 + kc * 8);
        }
#pragma unroll
        for (int it = 0; it < 4; it++) {
            int t = it * 256 + tid;
            int kc = t & 7, r = t >> 3;
            *(uint4*)&Bs[kc * PLANE + r * 8] =
                *(const uint4*)(B + (size_t)(n0 + r) * K + k0 + kc * 8);
        }
        __syncthreads();
#pragma unroll
        for (int s = 0; s < 2; s++) {
            bf16x8 af[4], bf[4];
#pragma unroll
            for (int i = 0; i < 4; i++)
                af[i] = *(const bf16x8*)&As[(s * 4 + quad) * PLANE + (m_base + i * 16 + row16) * 8];
#pragma unroll
            for (int j = 0; j < 4; j++)
                bf[j] = *(const bf16x8*)&Bs[(s * 4 + quad) * PLANE + (n_base + j * 16 + row16) * 8];
#pragma unroll
            for (int i = 0; i < 4; i++)
#pragma unroll
                for (int j = 0; j < 4; j++)
                    acc[i][j] = __builtin_amdgcn_mfma_f32_16x16x32_bf16(af[i], bf[j], acc[i][j], 0, 0, 0);
        }
        __syncthreads();
    }

#pragma unroll
    for (int i = 0; i < 4; i++) {
#pragma unroll
        for (int j = 0; j < 4; j++) {
            int col = n0 + n_base + j * 16 + row16;
            float bsv = bias[col];
#pragma unroll
            for (int r = 0; r < 4; r++) {
                int row = m0 + m_base + i * 16 + quad * 4 + r;
                float val = acc[i][j][r] + bsv;
                if (RESID) val += resid[(size_t)row * N + col];
                if (RELU) val = fmaxf(val, 0.0f);
                stfl(&C[(size_t)row * N + col], val);
            }
        }
    }
}

// ---------- K transpose: k_buf[(key*4+b)*512 + c] -> kT[((b*512)+c)*4096 + key] ----------
__global__ __launch_bounds__(256) void transpose_k(const bf16_t* __restrict__ kb,
                                                   bf16_t* __restrict__ kT) {
    __shared__ bf16_t tile[64][80];   // pad 80 -> 160B row stride, 16B aligned
    const int kt = blockIdx.x * 64;
    const int ct = blockIdx.y * 64;
    const int b  = blockIdx.z;
    const int t = threadIdx.x;

    // load 64 keys x 64 cols; thread: key_local = t>>2, col chunk (t&3)*16
    {
        int kl = t >> 2, cl = (t & 3) * 16;
        const bf16_t* src = kb + ((size_t)(kt + kl) * 4 + b) * 512 + ct + cl;
        *(uint4*)&tile[kl][cl]     = *(const uint4*)src;
        *(uint4*)&tile[kl][cl + 8] = *(const uint4*)(src + 8);
    }
    __syncthreads();
    // write: c_local = t>>2, keys (t&3)*16 .. +15
    {
        int cl2 = t >> 2, ks = (t & 3) * 16;
        __attribute__((aligned(16))) bf16_t vals[16];
#pragma unroll
        for (int j = 0; j < 16; j++) vals[j] = tile[ks + j][cl2];
        bf16_t* dst = kT + ((size_t)b * 512 + ct + cl2) * 4096 + kt + ks;
        *(uint4*)dst       = *(const uint4*)&vals[0];
        *(uint4*)(dst + 8) = *(const uint4*)&vals[8];
    }
}

// ---------- Fused windowed attention: q-pair per block, wave-per-head ----------
// grid (LQ/2, BATCH), 256 thr = 4 waves; wave w -> heads w, w+4; each wave does 2 queries.
__global__ __launch_bounds__(256, 4) void attn_kernel(
        const float* __restrict__ q, const bf16_t* __restrict__ kT,
        const bf16_t* __restrict__ v, bf16_t* __restrict__ ctx,
        float* __restrict__ attn_out) {
    const int q0 = blockIdx.x * 2;
    const int b  = blockIdx.y;
    const int tid = threadIdx.x;
    const int lane = tid & 63;
    const int w = tid >> 6;

    int s0 = q0 * 8, e0 = s0 + 827;
    if (e0 > LK - 1) { s0 -= e0 - (LK - 1); if (s0 < 0) s0 = 0; e0 = LK; }
    int s1 = (q0 + 1) * 8, e1 = s1 + 827;
    if (e1 > LK - 1) { s1 -= e1 - (LK - 1); if (s1 < 0) s1 = 0; e1 = LK; }
    const int us = s0;
    const int Wu = e1 - s0;          // <= 836 (< 896 = 7*128)
    const int lo1 = s1 - s0;         // q1 valid start (union-relative)
    const int hi0 = e0 - s0;         // q0 valid end (union-relative)

    __shared__ float2 qv2[DMODEL];
    __shared__ bf16_t p_lds[4][2][896];
    __shared__ bf16_t ap_lds[4][2][896];

    const size_t qrow0 = ((size_t)q0 * BATCH + b) * DMODEL;
    const size_t qrow1 = qrow0 + (size_t)BATCH * DMODEL;
    for (int i = tid; i < DMODEL; i += 256)
        qv2[i] = make_float2(q[qrow0 + i] * 0.125f, q[qrow1 + i] * 0.125f);
    __syncthreads();

    float ap[7][4];   // head-mean accumulators: [chunk][q0k0,q0k1,q1k0,q1k1]
#pragma unroll
    for (int c = 0; c < 7; c++) { ap[c][0] = 0; ap[c][1] = 0; ap[c][2] = 0; ap[c][3] = 0; }

    for (int hh = 0; hh < 2; hh++) {
        const int h = w + hh * 4;
        const int hoff = h * HEADDIM;

        // ---- scores: 7 chunks of 128 keys; lane handles keys (c*128 + lane*2, +1) ----
        float sc[7][4];
        float mx0 = -1e30f, mx1 = -1e30f;
#pragma unroll
        for (int c = 0; c < 7; c++) {
            int i0 = c * 128 + lane * 2;
            int key = (i0 < Wu) ? i0 : 0;
            const __hip_bfloat162* kp = reinterpret_cast<const __hip_bfloat162*>(
                kT + ((size_t)b * 512 + hoff) * 4096 + us + key);
            float d00 = 0, d01 = 0, d10 = 0, d11 = 0;
#pragma unroll 8
            for (int d = 0; d < 64; d++) {
                float2 kf = __bfloat1622float2(kp[(size_t)d * 2048]);
                float2 qd = qv2[hoff + d];
                d00 += qd.x * kf.x; d01 += qd.x * kf.y;
                d10 += qd.y * kf.x; d11 += qd.y * kf.y;
            }
            sc[c][0] = (i0 < hi0)                      ? d00 : -1e30f;
            sc[c][1] = (i0 + 1 < hi0)                  ? d01 : -1e30f;
            sc[c][2] = (i0 >= lo1 && i0 < Wu)          ? d10 : -1e30f;
            sc[c][3] = (i0 + 1 >= lo1 && i0 + 1 < Wu)  ? d11 : -1e30f;
            mx0 = fmaxf(mx0, fmaxf(sc[c][0], sc[c][1]));
            mx1 = fmaxf(mx1, fmaxf(sc[c][2], sc[c][3]));
        }
#pragma unroll
        for (int off = 32; off > 0; off >>= 1) {
            mx0 = fmaxf(mx0, __shfl_xor(mx0, off, 64));
            mx1 = fmaxf(mx1, __shfl_xor(mx1, off, 64));
        }
        float sm0 = 0, sm1 = 0;
#pragma unroll
        for (int c = 0; c < 7; c++) {
            sc[c][0] = __expf(sc[c][0] - mx0); sm0 += sc[c][0];
            sc[c][1] = __expf(sc[c][1] - mx0); sm0 += sc[c][1];
            sc[c][2] = __expf(sc[c][2] - mx1); sm1 += sc[c][2];
            sc[c][3] = __expf(sc[c][3] - mx1); sm1 += sc[c][3];
        }
#pragma unroll
        for (int off = 32; off > 0; off >>= 1) {
            sm0 += __shfl_xor(sm0, off, 64);
            sm1 += __shfl_xor(sm1, off, 64);
        }
        float inv0 = 1.0f / sm0, inv1 = 1.0f / sm1;
#pragma unroll
        for (int c = 0; c < 7; c++) {
            int i0 = c * 128 + lane * 2;
            float p00 = sc[c][0] * inv0, p01 = sc[c][1] * inv0;
            float p10 = sc[c][2] * inv1, p11 = sc[c][3] * inv1;
            bf16x2v v0; v0[0] = (__bf16)p00; v0[1] = (__bf16)p01;
            bf16x2v v1; v1[0] = (__bf16)p10; v1[1] = (__bf16)p11;
            *(bf16x2v*)&p_lds[w][0][i0] = v0;
            *(bf16x2v*)&p_lds[w][1][i0] = v1;
            ap[c][0] += p00 * 0.125f; ap[c][1] += p01 * 0.125f;
            ap[c][2] += p10 * 0.125f; ap[c][3] += p11 * 0.125f;
        }

        // ---- PV: lane owns dim `lane`; iterate union window ----
        const bf16_t* vb = v + ((size_t)us * BATCH + b) * DMODEL + hoff + lane;
        const int WR = (Wu + 3) & ~3;
        float a00 = 0, a01 = 0, a02 = 0, a03 = 0;
        float a10 = 0, a11 = 0, a12 = 0, a13 = 0;
        for (int i = 0; i < WR; i += 4) {
            bf16x4v p0 = *(const bf16x4v*)&p_lds[w][0][i];
            bf16x4v p1 = *(const bf16x4v*)&p_lds[w][1][i];
            float f0 = tofl(vb[(size_t)(i + 0) * 2048]);
            float f1 = tofl(vb[(size_t)(i + 1) * 2048]);
            float f2 = tofl(vb[(size_t)(i + 2) * 2048]);
            float f3 = tofl(vb[(size_t)(i + 3) * 2048]);
            a00 += (float)p0[0] * f0; a01 += (float)p0[1] * f1;
            a02 += (float)p0[2] * f2; a03 += (float)p0[3] * f3;
            a10 += (float)p1[0] * f0; a11 += (float)p1[1] * f1;
            a12 += (float)p1[2] * f2; a13 += (float)p1[3] * f3;
        }
        ctx[qrow0 + hoff + lane] = __float2bfloat16(a00 + a01 + a02 + a03);
        ctx[qrow1 + hoff + lane] = __float2bfloat16(a10 + a11 + a12 + a13);
    }

    // stash head-mean partials
#pragma unroll
    for (int c = 0; c < 7; c++) {
        int i0 = c * 128 + lane * 2;
        bf16x2v v0; v0[0] = (__bf16)ap[c][0]; v0[1] = (__bf16)ap[c][1];
        bf16x2v v1; v1[0] = (__bf16)ap[c][2]; v1[1] = (__bf16)ap[c][3];
        *(bf16x2v*)&ap_lds[w][0][i0] = v0;
        *(bf16x2v*)&ap_lds[w][1][i0] = v1;
    }
    __syncthreads();

    // attn_weights [B, LQ, LK]
#pragma unroll
    for (int qq = 0; qq < 2; qq++) {
        const size_t arow = ((size_t)b * LQ + q0 + qq) * (size_t)LK;
        const int sq = qq ? s1 : s0;
        const int eq = qq ? e1 : e0;
        for (int col = tid; col < LK; col += 256) {
            float pv = 0.0f;
            if (col >= sq && col < eq) {
                int i = col - us;
                pv = tofl(ap_lds[0][qq][i]) + tofl(ap_lds[1][qq][i]) +
                     tofl(ap_lds[2][qq][i]) + tofl(ap_lds[3][qq][i]);
            }
            attn_out[arow + col] = pv;
        }
    }
}

extern "C" void kernel_launch(void* const* d_in, const int* in_sizes, int n_in,
                              void* d_out, int out_size, void* d_ws, size_t ws_size,
                              hipStream_t stream) {
    const float* tgt    = (const float*)d_in[0];
    const float* memory = (const float*)d_in[1];
    const float* Wq = (const float*)d_in[2];
    const float* bq = (const float*)d_in[3];
    const float* Wk = (const float*)d_in[4];
    const float* bk = (const float*)d_in[5];
    const float* Wv = (const float*)d_in[6];
    const float* bv = (const float*)d_in[7];
    const float* Wo = (const float*)d_in[8];
    const float* bo = (const float*)d_in[9];
    const float* W1 = (const float*)d_in[10];
    const float* b1 = (const float*)d_in[11];
    const float* W2 = (const float*)d_in[12];
    const float* b2 = (const float*)d_in[13];
    const float* ln1w = (const float*)d_in[14];
    const float* ln1b = (const float*)d_in[15];
    const float* ln2w = (const float*)d_in[16];
    const float* ln2b = (const float*)d_in[17];
    const float* ln3w = (const float*)d_in[18];
    const float* ln3b = (const float*)d_in[19];
    const float* ln4w = (const float*)d_in[20];
    const float* ln4b = (const float*)d_in[21];

    const size_t M1 = (size_t)LQ * BATCH;      // 2048
    const size_t M2 = (size_t)LK * BATCH;      // 16384
    const size_t SZ1 = M1 * DMODEL;

    // ---- workspace (64 MiB, lifetime-aliased) ----
    // [0,16): m_buf(bf16) -> kT(bf16) -> {h_buf[0,8), xln_f[8,12), x2_buf[12,16)}
    // [16,32): k_buf   [32,48): v_buf
    // [48,50): t_bf -> xln_bf   [50,54): t_f32   [54,58): q_buf -> xres
    // [58,60): ctx_buf   [60,62): wqkvo   [62,64): wff
    char* wsb = (char*)d_ws;
    const size_t MB = 1 << 20;
    bf16_t* m_buf   = (bf16_t*)(wsb + 0 * MB);
    bf16_t* kT_buf  = (bf16_t*)(wsb + 0 * MB);
    bf16_t* h_buf   = (bf16_t*)(wsb + 0 * MB);
    float*  xln_f   = (float*)(wsb + 8 * MB);
    float*  x2_buf  = (float*)(wsb + 12 * MB);
    bf16_t* k_buf   = (bf16_t*)(wsb + 16 * MB);
    bf16_t* v_buf   = (bf16_t*)(wsb + 32 * MB);
    bf16_t* t_bf    = (bf16_t*)(wsb + 48 * MB);
    bf16_t* xln_bf  = (bf16_t*)(wsb + 48 * MB);
    float*  t_f32   = (float*)(wsb + 50 * MB);
    float*  q_buf   = (float*)(wsb + 54 * MB);
    float*  xres    = (float*)(wsb + 54 * MB);
    bf16_t* ctx_buf = (bf16_t*)(wsb + 58 * MB);
    bf16_t* wqkvo   = (bf16_t*)(wsb + 60 * MB);
    bf16_t* wff     = (bf16_t*)(wsb + 62 * MB);

    bf16_t* Wq_bf = wqkvo;
    bf16_t* Wk_bf = wqkvo + 262144;
    bf16_t* Wv_bf = wqkvo + 2 * 262144;
    bf16_t* Wo_bf = wqkvo + 3 * 262144;

    float* out_x    = (float*)d_out;
    float* out_attn = out_x + SZ1;

    conv4_kernel<<<dim3(1024), dim3(256), 0, stream>>>(Wq, Wk, Wv, Wo, wqkvo);

    ln_kernel<bf16_t, true><<<dim3(M1), dim3(256), 0, stream>>>(tgt, ln1w, ln1b, t_bf, t_f32);
    ln_kernel<bf16_t, false><<<dim3(M2), dim3(256), 0, stream>>>(memory, ln2w, ln2b, m_buf, nullptr);

    gemm_mfma<float, false, false><<<dim3(DMODEL / GBN, M1 / GBM), dim3(256), 0, stream>>>(
        t_bf, Wq_bf, bq, nullptr, q_buf, M1, DMODEL, DMODEL);
    gemm_mfma<bf16_t, false, false><<<dim3(DMODEL / GBN, M2 / GBM), dim3(256), 0, stream>>>(
        m_buf, Wk_bf, bk, nullptr, k_buf, M2, DMODEL, DMODEL);
    gemm_mfma<bf16_t, false, false><<<dim3(DMODEL / GBN, M2 / GBM), dim3(256), 0, stream>>>(
        m_buf, Wv_bf, bv, nullptr, v_buf, M2, DMODEL, DMODEL);

    // transpose K into b-planar layout (m_buf region is dead now)
    transpose_k<<<dim3(64, 8, 4), dim3(256), 0, stream>>>(k_buf, kT_buf);

    attn_kernel<<<dim3(LQ / 2, BATCH), dim3(256), 0, stream>>>(
        q_buf, kT_buf, v_buf, ctx_buf, out_attn);

    gemm_mfma<float, false, true><<<dim3(DMODEL / GBN, M1 / GBM), dim3(256), 0, stream>>>(
        ctx_buf, Wo_bf, bo, t_f32, xres, M1, DMODEL, DMODEL);

    ln_kernel<bf16_t, true><<<dim3(M1), dim3(256), 0, stream>>>(xres, ln3w, ln3b, xln_bf, xln_f);

    convw_kernel<<<dim3(1024), dim3(256), 0, stream>>>(W1, wff, DFF * DMODEL);
    gemm_mfma<bf16_t, true, false><<<dim3(DFF / GBN, M1 / GBM), dim3(256), 0, stream>>>(
        xln_bf, wff, b1, nullptr, h_buf, M1, DFF, DMODEL);

    convw_kernel<<<dim3(1024), dim3(256), 0, stream>>>(W2, wff, DMODEL * DFF);
    gemm_mfma<float, false, true><<<dim3(DMODEL / GBN, M1 / GBM), dim3(256), 0, stream>>>(
        h_buf, wff, b2, xln_f, x2_buf, M1, DMODEL, DFF);

    ln_kernel<float, false><<<dim3(M1), dim3(256), 0, stream>>>(x2_buf, ln4w, ln4b, out_x, nullptr);
}

// Round 6
// 456.974 us; speedup vs baseline: 4.4777x; 1.3193x over previous
//
#include <hip/hip_runtime.h>
#include <hip/hip_bf16.h>

typedef __hip_bfloat16 bf16_t;
typedef __bf16 bf16x8 __attribute__((ext_vector_type(8)));
typedef __bf16 bf16x4v __attribute__((ext_vector_type(4)));
typedef __bf16 bf16x2v __attribute__((ext_vector_type(2)));
typedef float f32x4 __attribute__((ext_vector_type(4)));

#define LQ 512
#define LK 4096
#define BATCH 4
#define DMODEL 512
#define NHEAD 8
#define HEADDIM 64
#define DFF 2048
#define LN_EPS 1e-5f

__device__ inline float tofl(float x) { return x; }
__device__ inline float tofl(bf16_t x) { return __bfloat162float(x); }
__device__ inline void stfl(float* p, float v) { *p = v; }
__device__ inline void stfl(bf16_t* p, float v) { *p = __float2bfloat16(v); }

// ---------- fp32 -> bf16 weight conversion ----------
__global__ void convw_kernel(const float* __restrict__ in, bf16_t* __restrict__ out, int n) {
    int i = (blockIdx.x * 256 + threadIdx.x) * 4;
    if (i + 3 < n) {
        float4 v = *(const float4*)(in + i);
        out[i + 0] = __float2bfloat16(v.x);
        out[i + 1] = __float2bfloat16(v.y);
        out[i + 2] = __float2bfloat16(v.z);
        out[i + 3] = __float2bfloat16(v.w);
    }
}
__global__ void conv4_kernel(const float* __restrict__ s0, const float* __restrict__ s1,
                             const float* __restrict__ s2, const float* __restrict__ s3,
                             bf16_t* __restrict__ dst) {
    int t = blockIdx.x * 256 + threadIdx.x;
    int which = t >> 16;
    int idx = (t & 65535) * 4;
    const float* s = which == 0 ? s0 : which == 1 ? s1 : which == 2 ? s2 : s3;
    float4 v = *(const float4*)(s + idx);
    bf16_t* d = dst + (size_t)which * 262144 + idx;
    d[0] = __float2bfloat16(v.x); d[1] = __float2bfloat16(v.y);
    d[2] = __float2bfloat16(v.z); d[3] = __float2bfloat16(v.w);
}

// ---------- LayerNorm ----------
template <typename TOUT, bool DUAL>
__global__ void ln_kernel(const float* __restrict__ in, const float* __restrict__ w,
                          const float* __restrict__ b, TOUT* __restrict__ out1,
                          float* __restrict__ out2) {
    __shared__ float red[256];
    const int row = blockIdx.x;
    const int tid = threadIdx.x;
    const float* x = in + (size_t)row * DMODEL;
    float v0 = x[tid];
    float v1 = x[tid + 256];

    red[tid] = v0 + v1;
    __syncthreads();
    for (int s = 128; s > 0; s >>= 1) { if (tid < s) red[tid] += red[tid + s]; __syncthreads(); }
    float mu = red[0] * (1.0f / DMODEL);
    __syncthreads();

    float d0 = v0 - mu, d1 = v1 - mu;
    red[tid] = d0 * d0 + d1 * d1;
    __syncthreads();
    for (int s = 128; s > 0; s >>= 1) { if (tid < s) red[tid] += red[tid + s]; __syncthreads(); }
    float inv = rsqrtf(red[0] * (1.0f / DMODEL) + LN_EPS);

    float r0 = d0 * inv * w[tid] + b[tid];
    float r1 = d1 * inv * w[tid + 256] + b[tid + 256];
    TOUT* o = out1 + (size_t)row * DMODEL;
    stfl(&o[tid], r0);
    stfl(&o[tid + 256], r1);
    if (DUAL) {
        float* o2 = out2 + (size_t)row * DMODEL;
        o2[tid] = r0;
        o2[tid + 256] = r1;
    }
}

// ---------- MFMA GEMM ----------
#define GBM 128
#define GBN 128
#define GBK 64
#define PLANE 1032
template <typename TC, bool RELU, bool RESID>
__global__ __launch_bounds__(256) void gemm_mfma(
        const bf16_t* __restrict__ A, const bf16_t* __restrict__ B,
        const float* __restrict__ bias, const float* __restrict__ resid,
        TC* __restrict__ C, int M, int N, int K) {
    __shared__ bf16_t As[8 * PLANE];
    __shared__ bf16_t Bs[8 * PLANE];

    const int tid = threadIdx.x;
    const int lane = tid & 63;
    const int wave = tid >> 6;
    const int wy = wave >> 1, wx = wave & 1;
    const int m_base = wy * 64, n_base = wx * 64;
    const int row16 = lane & 15;
    const int quad = lane >> 4;
    const int n0 = blockIdx.x * GBN;
    const int m0 = blockIdx.y * GBM;

    f32x4 acc[4][4] = {};

    for (int k0 = 0; k0 < K; k0 += GBK) {
#pragma unroll
        for (int it = 0; it < 4; it++) {
            int t = it * 256 + tid;
            int kc = t & 7, r = t >> 3;
            *(uint4*)&As[kc * PLANE + r * 8] =
                *(const uint4*)(A + (size_t)(m0 + r) * K + k0 + kc * 8);
        }
#pragma unroll
        for (int it = 0; it < 4; it++) {
            int t = it * 256 + tid;
            int kc = t & 7, r = t >> 3;
            *(uint4*)&Bs[kc * PLANE + r * 8] =
                *(const uint4*)(B + (size_t)(n0 + r) * K + k0 + kc * 8);
        }
        __syncthreads();
#pragma unroll
        for (int s = 0; s < 2; s++) {
            bf16x8 af[4], bf[4];
#pragma unroll
            for (int i = 0; i < 4; i++)
                af[i] = *(const bf16x8*)&As[(s * 4 + quad) * PLANE + (m_base + i * 16 + row16) * 8];
#pragma unroll
            for (int j = 0; j < 4; j++)
                bf[j] = *(const bf16x8*)&Bs[(s * 4 + quad) * PLANE + (n_base + j * 16 + row16) * 8];
#pragma unroll
            for (int i = 0; i < 4; i++)
#pragma unroll
                for (int j = 0; j < 4; j++)
                    acc[i][j] = __builtin_amdgcn_mfma_f32_16x16x32_bf16(af[i], bf[j], acc[i][j], 0, 0, 0);
        }
        __syncthreads();
    }

#pragma unroll
    for (int i = 0; i < 4; i++) {
#pragma unroll
        for (int j = 0; j < 4; j++) {
            int col = n0 + n_base + j * 16 + row16;
            float bsv = bias[col];
#pragma unroll
            for (int r = 0; r < 4; r++) {
                int row = m0 + m_base + i * 16 + quad * 4 + r;
                float val = acc[i][j][r] + bsv;
                if (RESID) val += resid[(size_t)row * N + col];
                if (RELU) val = fmaxf(val, 0.0f);
                stfl(&C[(size_t)row * N + col], val);
            }
        }
    }
}

// ---------- K transpose ----------
__global__ __launch_bounds__(256) void transpose_k(const bf16_t* __restrict__ kb,
                                                   bf16_t* __restrict__ kT) {
    __shared__ bf16_t tile[64][80];
    const int kt = blockIdx.x * 64;
    const int ct = blockIdx.y * 64;
    const int b  = blockIdx.z;
    const int t = threadIdx.x;
    {
        int kl = t >> 2, cl = (t & 3) * 16;
        const bf16_t* src = kb + ((size_t)(kt + kl) * 4 + b) * 512 + ct + cl;
        *(uint4*)&tile[kl][cl]     = *(const uint4*)src;
        *(uint4*)&tile[kl][cl + 8] = *(const uint4*)(src + 8);
    }
    __syncthreads();
    {
        int cl2 = t >> 2, ks = (t & 3) * 16;
        __attribute__((aligned(16))) bf16_t vals[16];
#pragma unroll
        for (int j = 0; j < 16; j++) vals[j] = tile[ks + j][cl2];
        bf16_t* dst = kT + ((size_t)b * 512 + ct + cl2) * 4096 + kt + ks;
        *(uint4*)dst       = *(const uint4*)&vals[0];
        *(uint4*)(dst + 8) = *(const uint4*)&vals[8];
    }
}

// ---------- Fused windowed attention: q-pair per block, wave-per-head, XCD swizzle ----------
// grid 1024 (1D), 512 thr = 8 waves; wave w = head w; block handles q-pair (2 queries).
// Swizzle: d&7 -> (b, q-half) group so each XCD sees one contiguous q-range of one b.
__global__ __launch_bounds__(512, 8) void attn_kernel(
        const float* __restrict__ q, const bf16_t* __restrict__ kT,
        const bf16_t* __restrict__ v, bf16_t* __restrict__ ctx,
        float* __restrict__ attn_out) {
    const int d = blockIdx.x;
    const int g = d & 7;
    const int i_in = d >> 3;            // 0..127
    const int b = g >> 1;
    const int qpair = (g & 1) * 128 + i_in;
    const int q0 = qpair * 2;
    const int tid = threadIdx.x;
    const int lane = tid & 63;
    const int w = tid >> 6;             // wave = head
    const int hoff = w * HEADDIM;

    int s0 = q0 * 8, e0 = s0 + 827;
    if (e0 > LK - 1) { s0 -= e0 - (LK - 1); if (s0 < 0) s0 = 0; e0 = LK; }
    int s1 = (q0 + 1) * 8, e1 = s1 + 827;
    if (e1 > LK - 1) { s1 -= e1 - (LK - 1); if (s1 < 0) s1 = 0; e1 = LK; }
    const int us = s0;
    const int Wu = e1 - s0;             // <= 836
    const int lo1 = s1 - s0;
    const int hi0 = e0 - s0;

    __shared__ float2 qv2[DMODEL];
    __shared__ bf16_t p_lds[8][2][896];

    const size_t qrow0 = ((size_t)q0 * BATCH + b) * DMODEL;
    const size_t qrow1 = qrow0 + (size_t)BATCH * DMODEL;
    for (int i = tid; i < DMODEL; i += 512)
        qv2[i] = make_float2(q[qrow0 + i] * 0.125f, q[qrow1 + i] * 0.125f);
    __syncthreads();

    // ---- scores: 7 chunks of 128 keys; lane handles keys (c*128 + lane*2, +1) ----
    float sc[7][4];
    float mx0 = -1e30f, mx1 = -1e30f;
#pragma unroll
    for (int c = 0; c < 7; c++) {
        int i0 = c * 128 + lane * 2;
        int key = (i0 < Wu) ? i0 : 0;
        const __hip_bfloat162* kp = reinterpret_cast<const __hip_bfloat162*>(
            kT + ((size_t)b * 512 + hoff) * 4096 + us + key);
        float d00 = 0, d01 = 0, d10 = 0, d11 = 0;
#pragma unroll 8
        for (int dd = 0; dd < 64; dd++) {
            float2 kf = __bfloat1622float2(kp[(size_t)dd * 2048]);
            float2 qd = qv2[hoff + dd];
            d00 += qd.x * kf.x; d01 += qd.x * kf.y;
            d10 += qd.y * kf.x; d11 += qd.y * kf.y;
        }
        sc[c][0] = (i0 < hi0)                      ? d00 : -1e30f;
        sc[c][1] = (i0 + 1 < hi0)                  ? d01 : -1e30f;
        sc[c][2] = (i0 >= lo1 && i0 < Wu)          ? d10 : -1e30f;
        sc[c][3] = (i0 + 1 >= lo1 && i0 + 1 < Wu)  ? d11 : -1e30f;
        mx0 = fmaxf(mx0, fmaxf(sc[c][0], sc[c][1]));
        mx1 = fmaxf(mx1, fmaxf(sc[c][2], sc[c][3]));
    }
#pragma unroll
    for (int off = 32; off > 0; off >>= 1) {
        mx0 = fmaxf(mx0, __shfl_xor(mx0, off, 64));
        mx1 = fmaxf(mx1, __shfl_xor(mx1, off, 64));
    }
    float sm0 = 0, sm1 = 0;
#pragma unroll
    for (int c = 0; c < 7; c++) {
        sc[c][0] = __expf(sc[c][0] - mx0); sm0 += sc[c][0];
        sc[c][1] = __expf(sc[c][1] - mx0); sm0 += sc[c][1];
        sc[c][2] = __expf(sc[c][2] - mx1); sm1 += sc[c][2];
        sc[c][3] = __expf(sc[c][3] - mx1); sm1 += sc[c][3];
    }
#pragma unroll
    for (int off = 32; off > 0; off >>= 1) {
        sm0 += __shfl_xor(sm0, off, 64);
        sm1 += __shfl_xor(sm1, off, 64);
    }
    float inv0 = 1.0f / sm0, inv1 = 1.0f / sm1;
#pragma unroll
    for (int c = 0; c < 7; c++) {
        int i0 = c * 128 + lane * 2;
        bf16x2v v0; v0[0] = (__bf16)(sc[c][0] * inv0); v0[1] = (__bf16)(sc[c][1] * inv0);
        bf16x2v v1; v1[0] = (__bf16)(sc[c][2] * inv1); v1[1] = (__bf16)(sc[c][3] * inv1);
        *(bf16x2v*)&p_lds[w][0][i0] = v0;
        *(bf16x2v*)&p_lds[w][1][i0] = v1;
    }

    // ---- PV: lane owns dim `lane` of this head ----
    {
        const bf16_t* vb = v + ((size_t)us * BATCH + b) * DMODEL + hoff + lane;
        const int WR = (Wu + 3) & ~3;
        float a00 = 0, a01 = 0, a02 = 0, a03 = 0;
        float a10 = 0, a11 = 0, a12 = 0, a13 = 0;
        for (int i = 0; i < WR; i += 4) {
            bf16x4v p0 = *(const bf16x4v*)&p_lds[w][0][i];
            bf16x4v p1 = *(const bf16x4v*)&p_lds[w][1][i];
            float f0 = tofl(vb[(size_t)(i + 0) * 2048]);
            float f1 = tofl(vb[(size_t)(i + 1) * 2048]);
            float f2 = tofl(vb[(size_t)(i + 2) * 2048]);
            float f3 = tofl(vb[(size_t)(i + 3) * 2048]);
            a00 += (float)p0[0] * f0; a01 += (float)p0[1] * f1;
            a02 += (float)p0[2] * f2; a03 += (float)p0[3] * f3;
            a10 += (float)p1[0] * f0; a11 += (float)p1[1] * f1;
            a12 += (float)p1[2] * f2; a13 += (float)p1[3] * f3;
        }
        ctx[qrow0 + hoff + lane] = __float2bfloat16(a00 + a01 + a02 + a03);
        ctx[qrow1 + hoff + lane] = __float2bfloat16(a10 + a11 + a12 + a13);
    }
    __syncthreads();

    // ---- attn_weights [B, LQ, LK]: mean over heads = sum of 8 wave p-planes * 0.125 ----
#pragma unroll
    for (int qq = 0; qq < 2; qq++) {
        const size_t arow = ((size_t)b * LQ + q0 + qq) * (size_t)LK;
        const int sq = qq ? s1 : s0;
        const int eq = qq ? e1 : e0;
        for (int col = tid; col < LK; col += 512) {
            float pv = 0.0f;
            if (col >= sq && col < eq) {
                int i = col - us;
                pv = (tofl(p_lds[0][qq][i]) + tofl(p_lds[1][qq][i]) +
                      tofl(p_lds[2][qq][i]) + tofl(p_lds[3][qq][i]) +
                      tofl(p_lds[4][qq][i]) + tofl(p_lds[5][qq][i]) +
                      tofl(p_lds[6][qq][i]) + tofl(p_lds[7][qq][i])) * 0.125f;
            }
            attn_out[arow + col] = pv;
        }
    }
}

extern "C" void kernel_launch(void* const* d_in, const int* in_sizes, int n_in,
                              void* d_out, int out_size, void* d_ws, size_t ws_size,
                              hipStream_t stream) {
    const float* tgt    = (const float*)d_in[0];
    const float* memory = (const float*)d_in[1];
    const float* Wq = (const float*)d_in[2];
    const float* bq = (const float*)d_in[3];
    const float* Wk = (const float*)d_in[4];
    const float* bk = (const float*)d_in[5];
    const float* Wv = (const float*)d_in[6];
    const float* bv = (const float*)d_in[7];
    const float* Wo = (const float*)d_in[8];
    const float* bo = (const float*)d_in[9];
    const float* W1 = (const float*)d_in[10];
    const float* b1 = (const float*)d_in[11];
    const float* W2 = (const float*)d_in[12];
    const float* b2 = (const float*)d_in[13];
    const float* ln1w = (const float*)d_in[14];
    const float* ln1b = (const float*)d_in[15];
    const float* ln2w = (const float*)d_in[16];
    const float* ln2b = (const float*)d_in[17];
    const float* ln3w = (const float*)d_in[18];
    const float* ln3b = (const float*)d_in[19];
    const float* ln4w = (const float*)d_in[20];
    const float* ln4b = (const float*)d_in[21];

    const size_t M1 = (size_t)LQ * BATCH;      // 2048
    const size_t M2 = (size_t)LK * BATCH;      // 16384
    const size_t SZ1 = M1 * DMODEL;

    char* wsb = (char*)d_ws;
    const size_t MB = 1 << 20;
    bf16_t* m_buf   = (bf16_t*)(wsb + 0 * MB);
    bf16_t* kT_buf  = (bf16_t*)(wsb + 0 * MB);
    bf16_t* h_buf   = (bf16_t*)(wsb + 0 * MB);
    float*  xln_f   = (float*)(wsb + 8 * MB);
    float*  x2_buf  = (float*)(wsb + 12 * MB);
    bf16_t* k_buf   = (bf16_t*)(wsb + 16 * MB);
    bf16_t* v_buf   = (bf16_t*)(wsb + 32 * MB);
    bf16_t* t_bf    = (bf16_t*)(wsb + 48 * MB);
    bf16_t* xln_bf  = (bf16_t*)(wsb + 48 * MB);
    float*  t_f32   = (float*)(wsb + 50 * MB);
    float*  q_buf   = (float*)(wsb + 54 * MB);
    float*  xres    = (float*)(wsb + 54 * MB);
    bf16_t* ctx_buf = (bf16_t*)(wsb + 58 * MB);
    bf16_t* wqkvo   = (bf16_t*)(wsb + 60 * MB);
    bf16_t* wff     = (bf16_t*)(wsb + 62 * MB);

    bf16_t* Wq_bf = wqkvo;
    bf16_t* Wk_bf = wqkvo + 262144;
    bf16_t* Wv_bf = wqkvo + 2 * 262144;
    bf16_t* Wo_bf = wqkvo + 3 * 262144;

    float* out_x    = (float*)d_out;
    float* out_attn = out_x + SZ1;

    conv4_kernel<<<dim3(1024), dim3(256), 0, stream>>>(Wq, Wk, Wv, Wo, wqkvo);

    ln_kernel<bf16_t, true><<<dim3(M1), dim3(256), 0, stream>>>(tgt, ln1w, ln1b, t_bf, t_f32);
    ln_kernel<bf16_t, false><<<dim3(M2), dim3(256), 0, stream>>>(memory, ln2w, ln2b, m_buf, nullptr);

    gemm_mfma<float, false, false><<<dim3(DMODEL / GBN, M1 / GBM), dim3(256), 0, stream>>>(
        t_bf, Wq_bf, bq, nullptr, q_buf, M1, DMODEL, DMODEL);
    gemm_mfma<bf16_t, false, false><<<dim3(DMODEL / GBN, M2 / GBM), dim3(256), 0, stream>>>(
        m_buf, Wk_bf, bk, nullptr, k_buf, M2, DMODEL, DMODEL);
    gemm_mfma<bf16_t, false, false><<<dim3(DMODEL / GBN, M2 / GBM), dim3(256), 0, stream>>>(
        m_buf, Wv_bf, bv, nullptr, v_buf, M2, DMODEL, DMODEL);

    transpose_k<<<dim3(64, 8, 4), dim3(256), 0, stream>>>(k_buf, kT_buf);

    attn_kernel<<<dim3(1024), dim3(512), 0, stream>>>(
        q_buf, kT_buf, v_buf, ctx_buf, out_attn);

    gemm_mfma<float, false, true><<<dim3(DMODEL / GBN, M1 / GBM), dim3(256), 0, stream>>>(
        ctx_buf, Wo_bf, bo, t_f32, xres, M1, DMODEL, DMODEL);

    ln_kernel<bf16_t, true><<<dim3(M1), dim3(256), 0, stream>>>(xres, ln3w, ln3b, xln_bf, xln_f);

    convw_kernel<<<dim3(1024), dim3(256), 0, stream>>>(W1, wff, DFF * DMODEL);
    gemm_mfma<bf16_t, true, false><<<dim3(DFF / GBN, M1 / GBM), dim3(256), 0, stream>>>(
        xln_bf, wff, b1, nullptr, h_buf, M1, DFF, DMODEL);

    convw_kernel<<<dim3(1024), dim3(256), 0, stream>>>(W2, wff, DMODEL * DFF);
    gemm_mfma<float, false, true><<<dim3(DMODEL / GBN, M1 / GBM), dim3(256), 0, stream>>>(
        h_buf, wff, b2, xln_f, x2_buf, M1, DMODEL, DFF);

    ln_kernel<float, false><<<dim3(M1), dim3(256), 0, stream>>>(x2_buf, ln4w, ln4b, out_x, nullptr);
}

// Round 7
// 378.954 us; speedup vs baseline: 5.3996x; 1.2059x over previous
//
#include <hip/hip_runtime.h>
#include <hip/hip_bf16.h>

typedef __hip_bfloat16 bf16_t;
typedef __bf16 bf16x8 __attribute__((ext_vector_type(8)));
typedef float f32x4 __attribute__((ext_vector_type(4)));

#define LQ 512
#define LK 4096
#define BATCH 4
#define DMODEL 512
#define NHEAD 8
#define HEADDIM 64
#define DFF 2048
#define LN_EPS 1e-5f

__device__ inline float tofl(float x) { return x; }
__device__ inline float tofl(bf16_t x) { return __bfloat162float(x); }
__device__ inline void stfl(float* p, float v) { *p = v; }
__device__ inline void stfl(bf16_t* p, float v) { *p = __float2bfloat16(v); }

// ---------- fp32 -> bf16 weight conversion ----------
__global__ void convw_kernel(const float* __restrict__ in, bf16_t* __restrict__ out, int n) {
    int i = (blockIdx.x * 256 + threadIdx.x) * 4;
    if (i + 3 < n) {
        float4 v = *(const float4*)(in + i);
        out[i + 0] = __float2bfloat16(v.x);
        out[i + 1] = __float2bfloat16(v.y);
        out[i + 2] = __float2bfloat16(v.z);
        out[i + 3] = __float2bfloat16(v.w);
    }
}
__global__ void conv4_kernel(const float* __restrict__ s0, const float* __restrict__ s1,
                             const float* __restrict__ s2, const float* __restrict__ s3,
                             bf16_t* __restrict__ dst) {
    int t = blockIdx.x * 256 + threadIdx.x;
    int which = t >> 16;
    int idx = (t & 65535) * 4;
    const float* s = which == 0 ? s0 : which == 1 ? s1 : which == 2 ? s2 : s3;
    float4 v = *(const float4*)(s + idx);
    bf16_t* d = dst + (size_t)which * 262144 + idx;
    d[0] = __float2bfloat16(v.x); d[1] = __float2bfloat16(v.y);
    d[2] = __float2bfloat16(v.z); d[3] = __float2bfloat16(v.w);
}

// ---------- LayerNorm ----------
template <typename TOUT, bool DUAL>
__global__ void ln_kernel(const float* __restrict__ in, const float* __restrict__ w,
                          const float* __restrict__ b, TOUT* __restrict__ out1,
                          float* __restrict__ out2) {
    __shared__ float red[256];
    const int row = blockIdx.x;
    const int tid = threadIdx.x;
    const float* x = in + (size_t)row * DMODEL;
    float v0 = x[tid];
    float v1 = x[tid + 256];

    red[tid] = v0 + v1;
    __syncthreads();
    for (int s = 128; s > 0; s >>= 1) { if (tid < s) red[tid] += red[tid + s]; __syncthreads(); }
    float mu = red[0] * (1.0f / DMODEL);
    __syncthreads();

    float d0 = v0 - mu, d1 = v1 - mu;
    red[tid] = d0 * d0 + d1 * d1;
    __syncthreads();
    for (int s = 128; s > 0; s >>= 1) { if (tid < s) red[tid] += red[tid + s]; __syncthreads(); }
    float inv = rsqrtf(red[0] * (1.0f / DMODEL) + LN_EPS);

    float r0 = d0 * inv * w[tid] + b[tid];
    float r1 = d1 * inv * w[tid + 256] + b[tid + 256];
    TOUT* o = out1 + (size_t)row * DMODEL;
    stfl(&o[tid], r0);
    stfl(&o[tid + 256], r1);
    if (DUAL) {
        float* o2 = out2 + (size_t)row * DMODEL;
        o2[tid] = r0;
        o2[tid + 256] = r1;
    }
}

// ---------- MFMA GEMM ----------
#define GBM 128
#define GBN 128
#define GBK 64
#define PLANE 1032
template <typename TC, bool RELU, bool RESID>
__global__ __launch_bounds__(256) void gemm_mfma(
        const bf16_t* __restrict__ A, const bf16_t* __restrict__ B,
        const float* __restrict__ bias, const float* __restrict__ resid,
        TC* __restrict__ C, int M, int N, int K) {
    __shared__ bf16_t As[8 * PLANE];
    __shared__ bf16_t Bs[8 * PLANE];

    const int tid = threadIdx.x;
    const int lane = tid & 63;
    const int wave = tid >> 6;
    const int wy = wave >> 1, wx = wave & 1;
    const int m_base = wy * 64, n_base = wx * 64;
    const int row16 = lane & 15;
    const int quad = lane >> 4;
    const int n0 = blockIdx.x * GBN;
    const int m0 = blockIdx.y * GBM;

    f32x4 acc[4][4] = {};

    for (int k0 = 0; k0 < K; k0 += GBK) {
#pragma unroll
        for (int it = 0; it < 4; it++) {
            int t = it * 256 + tid;
            int kc = t & 7, r = t >> 3;
            *(uint4*)&As[kc * PLANE + r * 8] =
                *(const uint4*)(A + (size_t)(m0 + r) * K + k0 + kc * 8);
        }
#pragma unroll
        for (int it = 0; it < 4; it++) {
            int t = it * 256 + tid;
            int kc = t & 7, r = t >> 3;
            *(uint4*)&Bs[kc * PLANE + r * 8] =
                *(const uint4*)(B + (size_t)(n0 + r) * K + k0 + kc * 8);
        }
        __syncthreads();
#pragma unroll
        for (int s = 0; s < 2; s++) {
            bf16x8 af[4], bf[4];
#pragma unroll
            for (int i = 0; i < 4; i++)
                af[i] = *(const bf16x8*)&As[(s * 4 + quad) * PLANE + (m_base + i * 16 + row16) * 8];
#pragma unroll
            for (int j = 0; j < 4; j++)
                bf[j] = *(const bf16x8*)&Bs[(s * 4 + quad) * PLANE + (n_base + j * 16 + row16) * 8];
#pragma unroll
            for (int i = 0; i < 4; i++)
#pragma unroll
                for (int j = 0; j < 4; j++)
                    acc[i][j] = __builtin_amdgcn_mfma_f32_16x16x32_bf16(af[i], bf[j], acc[i][j], 0, 0, 0);
        }
        __syncthreads();
    }

#pragma unroll
    for (int i = 0; i < 4; i++) {
#pragma unroll
        for (int j = 0; j < 4; j++) {
            int col = n0 + n_base + j * 16 + row16;
            float bsv = bias[col];
#pragma unroll
            for (int r = 0; r < 4; r++) {
                int row = m0 + m_base + i * 16 + quad * 4 + r;
                float val = acc[i][j][r] + bsv;
                if (RESID) val += resid[(size_t)row * N + col];
                if (RELU) val = fmaxf(val, 0.0f);
                stfl(&C[(size_t)row * N + col], val);
            }
        }
    }
}

// ---------- transpose: in[(key*4+b)*512 + c] -> out[(b*512+c)*4096 + key] ----------
__global__ __launch_bounds__(256) void transpose_kv(const bf16_t* __restrict__ kb,
                                                    bf16_t* __restrict__ kT) {
    __shared__ bf16_t tile[64][80];
    const int kt = blockIdx.x * 64;
    const int ct = blockIdx.y * 64;
    const int b  = blockIdx.z;
    const int t = threadIdx.x;
    {
        int kl = t >> 2, cl = (t & 3) * 16;
        const bf16_t* src = kb + ((size_t)(kt + kl) * 4 + b) * 512 + ct + cl;
        *(uint4*)&tile[kl][cl]     = *(const uint4*)src;
        *(uint4*)&tile[kl][cl + 8] = *(const uint4*)(src + 8);
    }
    __syncthreads();
    {
        int cl2 = t >> 2, ks = (t & 3) * 16;
        __attribute__((aligned(16))) bf16_t vals[16];
#pragma unroll
        for (int j = 0; j < 16; j++) vals[j] = tile[ks + j][cl2];
        bf16_t* dst = kT + ((size_t)b * 512 + ct + cl2) * 4096 + kt + ks;
        *(uint4*)dst       = *(const uint4*)&vals[0];
        *(uint4*)(dst + 8) = *(const uint4*)&vals[8];
    }
}

// ---------- MFMA flash attention ----------
// grid 256 = (qt 0..63) x (b 0..3), 512 thr = 8 waves = 8 heads; 8-query tile.
// No max-subtraction (scores bounded); 2-pass: l-sum, then normalized P + PV + p-mean out.
__global__ __launch_bounds__(512, 2) void attn_mfma(
        const bf16_t* __restrict__ qb,   // [2048,512] rows (q*4+b)
        const bf16_t* __restrict__ kb,   // [16384,512] rows (key*4+b)
        const bf16_t* __restrict__ vT,   // [4][512][4096]
        bf16_t* __restrict__ ctx,        // [2048,512]
        float* __restrict__ attn_out) {  // [4][512][4096]
    const int blk = blockIdx.x;
    const int b  = blk & 3;
    const int qt = blk >> 2;
    const int q0 = qt * 8;
    const int tid = threadIdx.x;
    const int lane = tid & 63;
    const int w = tid >> 6;          // head
    const int hoff = w * HEADDIM;
    const int row16 = lane & 15;
    const int quad = lane >> 4;

    __shared__ bf16_t Qs[16][528];         // 8 real q rows + 8 zero rows, padded
    __shared__ bf16_t Ps[8][16][136];      // per-head P chunk [q][key], padded

    // union window start
    int us; { int s = q0 * 8, e = s + 827; if (e > 4095) s = 3268; us = s; }
    // per-lane q-row windows (q = quad*4+r), empty for pad rows
    int sq[4], eq[4];
#pragma unroll
    for (int r = 0; r < 4; r++) {
        int ql = quad * 4 + r;
        if (ql < 8) {
            int s = (q0 + ql) * 8, e = s + 827;
            if (e > 4095) { s = 3268; e = 4096; }
            sq[r] = s; eq[r] = e;
        } else { sq[r] = 0; eq[r] = 0; }
    }

    // stage Q (rows 0..7), zero rows 8..15
    {
        int r = tid >> 6, off = (tid & 63) * 8;
        *(uint4*)&Qs[r][off] = *(const uint4*)(qb + ((size_t)(q0 + r) * 4 + b) * 512 + off);
        uint4 z = {0, 0, 0, 0};
        *(uint4*)&Qs[r + 8][off] = z;
    }
    __syncthreads();

    const bf16x8 aq0 = *(const bf16x8*)&Qs[row16][hoff + quad * 8];
    const bf16x8 aq1 = *(const bf16x8*)&Qs[row16][hoff + 32 + quad * 8];

    // ---- pass 1: row sums l ----
    float l[4] = {0.f, 0.f, 0.f, 0.f};
    for (int c = 0; c < 7; c++) {
        const int cb = c * 128;
#pragma unroll
        for (int t = 0; t < 8; t++) {
            int key = us + cb + t * 16 + row16;
            int key_eff = key > 4095 ? 4095 : key;
            const bf16_t* kr = kb + ((size_t)key_eff * 4 + b) * 512 + hoff;
            bf16x8 bk0 = *(const bf16x8*)(kr + quad * 8);
            bf16x8 bk1 = *(const bf16x8*)(kr + 32 + quad * 8);
            f32x4 acc = {};
            acc = __builtin_amdgcn_mfma_f32_16x16x32_bf16(aq0, bk0, acc, 0, 0, 0);
            acc = __builtin_amdgcn_mfma_f32_16x16x32_bf16(aq1, bk1, acc, 0, 0, 0);
#pragma unroll
            for (int r = 0; r < 4; r++) {
                bool valid = (key >= sq[r]) && (key < eq[r]);
                l[r] += valid ? __expf(0.125f * acc[r]) : 0.0f;
            }
        }
    }
    // reduce l across the 16 lanes of each quad-group
#pragma unroll
    for (int off = 1; off < 16; off <<= 1) {
#pragma unroll
        for (int r = 0; r < 4; r++) l[r] += __shfl_xor(l[r], off, 64);
    }
    float linv[4];
#pragma unroll
    for (int r = 0; r < 4; r++) linv[r] = 1.0f / l[r];

    // ---- pass 2: normalized P -> LDS, p-mean out, PV ----
    f32x4 o[4] = {};
    for (int c = 0; c < 7; c++) {
        const int cb = c * 128;
#pragma unroll
        for (int t = 0; t < 8; t++) {
            int key = us + cb + t * 16 + row16;
            int key_eff = key > 4095 ? 4095 : key;
            const bf16_t* kr = kb + ((size_t)key_eff * 4 + b) * 512 + hoff;
            bf16x8 bk0 = *(const bf16x8*)(kr + quad * 8);
            bf16x8 bk1 = *(const bf16x8*)(kr + 32 + quad * 8);
            f32x4 acc = {};
            acc = __builtin_amdgcn_mfma_f32_16x16x32_bf16(aq0, bk0, acc, 0, 0, 0);
            acc = __builtin_amdgcn_mfma_f32_16x16x32_bf16(aq1, bk1, acc, 0, 0, 0);
#pragma unroll
            for (int r = 0; r < 4; r++) {
                bool valid = (key >= sq[r]) && (key < eq[r]);
                float p = valid ? __expf(0.125f * acc[r]) * linv[r] : 0.0f;
                Ps[w][quad * 4 + r][t * 16 + row16] = __float2bfloat16(p);
            }
        }
        __syncthreads();

        // head-mean attn_out for this chunk (final values; P already normalized)
        {
            int qq = tid >> 6;              // 0..7
            int c2 = (tid & 63) * 2;
            int col = us + cb + c2;
            if (col < 4096) {
                float s0 = 0.f, s1 = 0.f;
#pragma unroll
                for (int h = 0; h < 8; h++) {
                    s0 += tofl(Ps[h][qq][c2]);
                    s1 += tofl(Ps[h][qq][c2 + 1]);
                }
                float2 out2 = make_float2(s0 * 0.125f, s1 * 0.125f);
                *(float2*)&attn_out[((size_t)b * LQ + q0 + qq) * LK + col] = out2;
            }
        }

        // PV: O += P_chunk x V_chunk
#pragma unroll
        for (int kt = 0; kt < 4; kt++) {
            bf16x8 ap = *(const bf16x8*)&Ps[w][row16][kt * 32 + quad * 8];
#pragma unroll
            for (int nt = 0; nt < 4; nt++) {
                const bf16_t* vr = vT + ((size_t)b * 512 + hoff + nt * 16 + row16) * 4096
                                   + us + cb + kt * 32 + quad * 8;
                bf16x8 bv = *(const bf16x8*)vr;
                o[nt] = __builtin_amdgcn_mfma_f32_16x16x32_bf16(ap, bv, o[nt], 0, 0, 0);
            }
        }
        __syncthreads();
    }

    // ---- ctx write ----
#pragma unroll
    for (int nt = 0; nt < 4; nt++) {
#pragma unroll
        for (int r = 0; r < 4; r++) {
            int ql = quad * 4 + r;
            if (ql < 8) {
                ctx[((size_t)(q0 + ql) * 4 + b) * 512 + hoff + nt * 16 + row16] =
                    __float2bfloat16(o[nt][r]);
            }
        }
    }

    // ---- zero-fill attn_out outside [us, us+896) ----
    for (int j = tid; j < 8 * 1024; j += 512) {
        int qq = j >> 10;
        int col = (j & 1023) * 4;
        if (col < us || col >= us + 896) {
            float4 z = {0.f, 0.f, 0.f, 0.f};
            *(float4*)&attn_out[((size_t)b * LQ + q0 + qq) * LK + col] = z;
        }
    }
}

extern "C" void kernel_launch(void* const* d_in, const int* in_sizes, int n_in,
                              void* d_out, int out_size, void* d_ws, size_t ws_size,
                              hipStream_t stream) {
    const float* tgt    = (const float*)d_in[0];
    const float* memory = (const float*)d_in[1];
    const float* Wq = (const float*)d_in[2];
    const float* bq = (const float*)d_in[3];
    const float* Wk = (const float*)d_in[4];
    const float* bk = (const float*)d_in[5];
    const float* Wv = (const float*)d_in[6];
    const float* bv = (const float*)d_in[7];
    const float* Wo = (const float*)d_in[8];
    const float* bo = (const float*)d_in[9];
    const float* W1 = (const float*)d_in[10];
    const float* b1 = (const float*)d_in[11];
    const float* W2 = (const float*)d_in[12];
    const float* b2 = (const float*)d_in[13];
    const float* ln1w = (const float*)d_in[14];
    const float* ln1b = (const float*)d_in[15];
    const float* ln2w = (const float*)d_in[16];
    const float* ln2b = (const float*)d_in[17];
    const float* ln3w = (const float*)d_in[18];
    const float* ln3b = (const float*)d_in[19];
    const float* ln4w = (const float*)d_in[20];
    const float* ln4b = (const float*)d_in[21];

    const size_t M1 = (size_t)LQ * BATCH;      // 2048
    const size_t M2 = (size_t)LK * BATCH;      // 16384
    const size_t SZ1 = M1 * DMODEL;

    // ---- workspace (64 MiB, lifetime-aliased) ----
    // [0,16): m_buf -> vT -> {h_buf[0,8), xln_f[8,12), x2_buf[12,16)}
    // [16,32): k_buf   [32,48): v_buf
    // [48,50): t_bf -> xln_bf   [50,54): t_f32
    // [54,56): q_bf (bf16);  [54,58): xres (fp32, after attn)
    // [58,60): ctx_buf   [60,62): wqkvo   [62,64): wff
    char* wsb = (char*)d_ws;
    const size_t MB = 1 << 20;
    bf16_t* m_buf   = (bf16_t*)(wsb + 0 * MB);
    bf16_t* vT_buf  = (bf16_t*)(wsb + 0 * MB);
    bf16_t* h_buf   = (bf16_t*)(wsb + 0 * MB);
    float*  xln_f   = (float*)(wsb + 8 * MB);
    float*  x2_buf  = (float*)(wsb + 12 * MB);
    bf16_t* k_buf   = (bf16_t*)(wsb + 16 * MB);
    bf16_t* v_buf   = (bf16_t*)(wsb + 32 * MB);
    bf16_t* t_bf    = (bf16_t*)(wsb + 48 * MB);
    bf16_t* xln_bf  = (bf16_t*)(wsb + 48 * MB);
    float*  t_f32   = (float*)(wsb + 50 * MB);
    bf16_t* q_bf    = (bf16_t*)(wsb + 54 * MB);
    float*  xres    = (float*)(wsb + 54 * MB);
    bf16_t* ctx_buf = (bf16_t*)(wsb + 58 * MB);
    bf16_t* wqkvo   = (bf16_t*)(wsb + 60 * MB);
    bf16_t* wff     = (bf16_t*)(wsb + 62 * MB);

    bf16_t* Wq_bf = wqkvo;
    bf16_t* Wk_bf = wqkvo + 262144;
    bf16_t* Wv_bf = wqkvo + 2 * 262144;
    bf16_t* Wo_bf = wqkvo + 3 * 262144;

    float* out_x    = (float*)d_out;
    float* out_attn = out_x + SZ1;

    conv4_kernel<<<dim3(1024), dim3(256), 0, stream>>>(Wq, Wk, Wv, Wo, wqkvo);

    ln_kernel<bf16_t, true><<<dim3(M1), dim3(256), 0, stream>>>(tgt, ln1w, ln1b, t_bf, t_f32);
    ln_kernel<bf16_t, false><<<dim3(M2), dim3(256), 0, stream>>>(memory, ln2w, ln2b, m_buf, nullptr);

    gemm_mfma<bf16_t, false, false><<<dim3(DMODEL / GBN, M1 / GBM), dim3(256), 0, stream>>>(
        t_bf, Wq_bf, bq, nullptr, q_bf, M1, DMODEL, DMODEL);
    gemm_mfma<bf16_t, false, false><<<dim3(DMODEL / GBN, M2 / GBM), dim3(256), 0, stream>>>(
        m_buf, Wk_bf, bk, nullptr, k_buf, M2, DMODEL, DMODEL);
    gemm_mfma<bf16_t, false, false><<<dim3(DMODEL / GBN, M2 / GBM), dim3(256), 0, stream>>>(
        m_buf, Wv_bf, bv, nullptr, v_buf, M2, DMODEL, DMODEL);

    // V transpose to [b][d][key] (m_buf dead -> vT region)
    transpose_kv<<<dim3(64, 8, 4), dim3(256), 0, stream>>>(v_buf, vT_buf);

    attn_mfma<<<dim3(256), dim3(512), 0, stream>>>(q_bf, k_buf, vT_buf, ctx_buf, out_attn);

    gemm_mfma<float, false, true><<<dim3(DMODEL / GBN, M1 / GBM), dim3(256), 0, stream>>>(
        ctx_buf, Wo_bf, bo, t_f32, xres, M1, DMODEL, DMODEL);

    ln_kernel<bf16_t, true><<<dim3(M1), dim3(256), 0, stream>>>(xres, ln3w, ln3b, xln_bf, xln_f);

    convw_kernel<<<dim3(1024), dim3(256), 0, stream>>>(W1, wff, DFF * DMODEL);
    gemm_mfma<bf16_t, true, false><<<dim3(DFF / GBN, M1 / GBM), dim3(256), 0, stream>>>(
        xln_bf, wff, b1, nullptr, h_buf, M1, DFF, DMODEL);

    convw_kernel<<<dim3(1024), dim3(256), 0, stream>>>(W2, wff, DMODEL * DFF);
    gemm_mfma<float, false, true><<<dim3(DMODEL / GBN, M1 / GBM), dim3(256), 0, stream>>>(
        h_buf, wff, b2, xln_f, x2_buf, M1, DMODEL, DFF);

    ln_kernel<float, false><<<dim3(M1), dim3(256), 0, stream>>>(x2_buf, ln4w, ln4b, out_x, nullptr);
}

// Round 9
// 364.158 us; speedup vs baseline: 5.6190x; 1.0406x over previous
//
#include <hip/hip_runtime.h>
#include <hip/hip_bf16.h>

typedef __hip_bfloat16 bf16_t;
typedef __bf16 bf16x8 __attribute__((ext_vector_type(8)));
typedef float f32x4 __attribute__((ext_vector_type(4)));

#define LQ 512
#define LK 4096
#define BATCH 4
#define DMODEL 512
#define NHEAD 8
#define HEADDIM 64
#define DFF 2048
#define LN_EPS 1e-5f

__device__ inline float tofl(float x) { return x; }
__device__ inline float tofl(bf16_t x) { return __bfloat162float(x); }
__device__ inline void stfl(float* p, float v) { *p = v; }
__device__ inline void stfl(bf16_t* p, float v) { *p = __float2bfloat16(v); }

// ---------- fp32 -> bf16 weight conversion ----------
__global__ void convw_kernel(const float* __restrict__ in, bf16_t* __restrict__ out, int n) {
    int i = (blockIdx.x * 256 + threadIdx.x) * 4;
    if (i + 3 < n) {
        float4 v = *(const float4*)(in + i);
        out[i + 0] = __float2bfloat16(v.x);
        out[i + 1] = __float2bfloat16(v.y);
        out[i + 2] = __float2bfloat16(v.z);
        out[i + 3] = __float2bfloat16(v.w);
    }
}
__global__ void conv4_kernel(const float* __restrict__ s0, const float* __restrict__ s1,
                             const float* __restrict__ s2, const float* __restrict__ s3,
                             bf16_t* __restrict__ dst) {
    int t = blockIdx.x * 256 + threadIdx.x;
    int which = t >> 16;
    int idx = (t & 65535) * 4;
    const float* s = which == 0 ? s0 : which == 1 ? s1 : which == 2 ? s2 : s3;
    float4 v = *(const float4*)(s + idx);
    bf16_t* d = dst + (size_t)which * 262144 + idx;
    d[0] = __float2bfloat16(v.x); d[1] = __float2bfloat16(v.y);
    d[2] = __float2bfloat16(v.z); d[3] = __float2bfloat16(v.w);
}

// ---------- zero-fill attn_out ----------
__global__ void zero_attn(float* __restrict__ p) {
    size_t i = ((size_t)blockIdx.x * 256 + threadIdx.x) * 4;
    float4 z = {0.f, 0.f, 0.f, 0.f};
    *(float4*)(p + i) = z;
}

// ---------- LayerNorm ----------
template <typename TOUT, bool DUAL>
__global__ void ln_kernel(const float* __restrict__ in, const float* __restrict__ w,
                          const float* __restrict__ b, TOUT* __restrict__ out1,
                          float* __restrict__ out2) {
    __shared__ float red[256];
    const int row = blockIdx.x;
    const int tid = threadIdx.x;
    const float* x = in + (size_t)row * DMODEL;
    float v0 = x[tid];
    float v1 = x[tid + 256];

    red[tid] = v0 + v1;
    __syncthreads();
    for (int s = 128; s > 0; s >>= 1) { if (tid < s) red[tid] += red[tid + s]; __syncthreads(); }
    float mu = red[0] * (1.0f / DMODEL);
    __syncthreads();

    float d0 = v0 - mu, d1 = v1 - mu;
    red[tid] = d0 * d0 + d1 * d1;
    __syncthreads();
    for (int s = 128; s > 0; s >>= 1) { if (tid < s) red[tid] += red[tid + s]; __syncthreads(); }
    float inv = rsqrtf(red[0] * (1.0f / DMODEL) + LN_EPS);

    float r0 = d0 * inv * w[tid] + b[tid];
    float r1 = d1 * inv * w[tid + 256] + b[tid + 256];
    TOUT* o = out1 + (size_t)row * DMODEL;
    stfl(&o[tid], r0);
    stfl(&o[tid + 256], r1);
    if (DUAL) {
        float* o2 = out2 + (size_t)row * DMODEL;
        o2[tid] = r0;
        o2[tid + 256] = r1;
    }
}

// ---------- MFMA GEMM ----------
#define GBM 128
#define GBN 128
#define GBK 64
#define PLANE 1032
template <typename TC, bool RELU, bool RESID>
__global__ __launch_bounds__(256) void gemm_mfma(
        const bf16_t* __restrict__ A, const bf16_t* __restrict__ B,
        const float* __restrict__ bias, const float* __restrict__ resid,
        TC* __restrict__ C, int M, int N, int K) {
    __shared__ bf16_t As[8 * PLANE];
    __shared__ bf16_t Bs[8 * PLANE];

    const int tid = threadIdx.x;
    const int lane = tid & 63;
    const int wave = tid >> 6;
    const int wy = wave >> 1, wx = wave & 1;
    const int m_base = wy * 64, n_base = wx * 64;
    const int row16 = lane & 15;
    const int quad = lane >> 4;
    const int n0 = blockIdx.x * GBN;
    const int m0 = blockIdx.y * GBM;

    f32x4 acc[4][4] = {};

    for (int k0 = 0; k0 < K; k0 += GBK) {
#pragma unroll
        for (int it = 0; it < 4; it++) {
            int t = it * 256 + tid;
            int kc = t & 7, r = t >> 3;
            *(uint4*)&As[kc * PLANE + r * 8] =
                *(const uint4*)(A + (size_t)(m0 + r) * K + k0 + kc * 8);
        }
#pragma unroll
        for (int it = 0; it < 4; it++) {
            int t = it * 256 + tid;
            int kc = t & 7, r = t >> 3;
            *(uint4*)&Bs[kc * PLANE + r * 8] =
                *(const uint4*)(B + (size_t)(n0 + r) * K + k0 + kc * 8);
        }
        __syncthreads();
#pragma unroll
        for (int s = 0; s < 2; s++) {
            bf16x8 af[4], bf[4];
#pragma unroll
            for (int i = 0; i < 4; i++)
                af[i] = *(const bf16x8*)&As[(s * 4 + quad) * PLANE + (m_base + i * 16 + row16) * 8];
#pragma unroll
            for (int j = 0; j < 4; j++)
                bf[j] = *(const bf16x8*)&Bs[(s * 4 + quad) * PLANE + (n_base + j * 16 + row16) * 8];
#pragma unroll
            for (int i = 0; i < 4; i++)
#pragma unroll
                for (int j = 0; j < 4; j++)
                    acc[i][j] = __builtin_amdgcn_mfma_f32_16x16x32_bf16(af[i], bf[j], acc[i][j], 0, 0, 0);
        }
        __syncthreads();
    }

#pragma unroll
    for (int i = 0; i < 4; i++) {
#pragma unroll
        for (int j = 0; j < 4; j++) {
            int col = n0 + n_base + j * 16 + row16;
            float bsv = bias[col];
#pragma unroll
            for (int r = 0; r < 4; r++) {
                int row = m0 + m_base + i * 16 + quad * 4 + r;
                float val = acc[i][j][r] + bsv;
                if (RESID) val += resid[(size_t)row * N + col];
                if (RELU) val = fmaxf(val, 0.0f);
                stfl(&C[(size_t)row * N + col], val);
            }
        }
    }
}

// ---------- transpose: in[(key*4+b)*512 + c] -> out[(b*512+c)*4096 + key] ----------
__global__ __launch_bounds__(256) void transpose_kv(const bf16_t* __restrict__ kb,
                                                    bf16_t* __restrict__ kT) {
    __shared__ bf16_t tile[64][80];
    const int kt = blockIdx.x * 64;
    const int ct = blockIdx.y * 64;
    const int b  = blockIdx.z;
    const int t = threadIdx.x;
    {
        int kl = t >> 2, cl = (t & 3) * 16;
        const bf16_t* src = kb + ((size_t)(kt + kl) * 4 + b) * 512 + ct + cl;
        *(uint4*)&tile[kl][cl]     = *(const uint4*)src;
        *(uint4*)&tile[kl][cl + 8] = *(const uint4*)(src + 8);
    }
    __syncthreads();
    {
        int cl2 = t >> 2, ks = (t & 3) * 16;
        __attribute__((aligned(16))) bf16_t vals[16];
#pragma unroll
        for (int j = 0; j < 16; j++) vals[j] = tile[ks + j][cl2];
        bf16_t* dst = kT + ((size_t)b * 512 + ct + cl2) * 4096 + kt + ks;
        *(uint4*)dst       = *(const uint4*)&vals[0];
        *(uint4*)(dst + 8) = *(const uint4*)&vals[8];
    }
}

// ---------- MFMA flash attention, single pass ----------
// grid 512: d&7 -> (b, q-half), d>>3 -> (hg, qt-contig). 256 thr = 4 waves = 4 heads.
// Unnormalized P in LDS for full window; l accumulated in-pass; O scaled by 1/l at end;
// attn_out = sum over head-groups via atomicAdd onto pre-zeroed buffer.
__global__ __launch_bounds__(256, 2) void attn_mfma(
        const bf16_t* __restrict__ qb,   // [2048,512] rows (q*4+b)
        const bf16_t* __restrict__ kb,   // [16384,512] rows (key*4+b)
        const bf16_t* __restrict__ vT,   // [4][512][4096]
        bf16_t* __restrict__ ctx,        // [2048,512]
        float* __restrict__ attn_out) {  // [4][512][4096], pre-zeroed
    const int d = blockIdx.x;
    const int g = d & 7;
    const int b = g >> 1;
    const int qhalf = g & 1;
    const int i_in = d >> 3;             // 0..63
    const int hg = i_in & 1;
    const int qt = qhalf * 32 + (i_in >> 1);
    const int q0 = qt * 8;
    const int tid = threadIdx.x;
    const int lane = tid & 63;
    const int w = tid >> 6;              // local head 0..3
    const int h = hg * 4 + w;
    const int hoffg = h * HEADDIM;       // global dim offset
    const int hl = w * HEADDIM;          // offset within Qs (256-dim slice)
    const int row16 = lane & 15;
    const int quad = lane >> 4;

    __align__(16) __shared__ bf16_t Qs[8][264];
    __align__(16) __shared__ bf16_t Zrow[904];
    __align__(16) __shared__ bf16_t Ps[4][8][904];
    __shared__ float Ls[4][8];

    // union window start
    int us; { int s = q0 * 8, e = s + 827; if (e > 4095) s = 3268; us = s; }
    // per-lane q-row windows (q = quad*4+r); empty for rows >= 8
    int sq[4], eq[4];
#pragma unroll
    for (int r = 0; r < 4; r++) {
        int ql = quad * 4 + r;
        if (ql < 8) {
            int s = (q0 + ql) * 8, e = s + 827;
            if (e > 4095) { s = 3268; e = 4096; }
            sq[r] = s; eq[r] = e;
        } else { sq[r] = 0; eq[r] = 0; }
    }

    // stage Q slice (8 rows x 256 dims of this head-group) + zero row
    {
        int r = tid >> 5, coff = (tid & 31) * 8;
        *(uint4*)&Qs[r][coff] =
            *(const uint4*)(qb + ((size_t)(q0 + r) * 4 + b) * 512 + hg * 256 + coff);
        if (tid < 113) { uint4 z = {0, 0, 0, 0}; *(uint4*)&Zrow[tid * 8] = z; }
    }
    __syncthreads();

    const bf16_t* q0p = (row16 < 8) ? &Qs[row16][hl + quad * 8] : &Zrow[0];
    const bf16_t* q1p = (row16 < 8) ? &Qs[row16][hl + 32 + quad * 8] : &Zrow[8];
    const bf16x8 aq0 = *(const bf16x8*)q0p;
    const bf16x8 aq1 = *(const bf16x8*)q1p;

    // ---- single QK pass: scores -> exp (unnormalized) -> Ps + l ----
    float l[4] = {0.f, 0.f, 0.f, 0.f};
    for (int c = 0; c < 7; c++) {
        const int cb = c * 128;
#pragma unroll
        for (int t8 = 0; t8 < 8; t8++) {
            int key = us + cb + t8 * 16 + row16;
            int key_eff = key > 4095 ? 4095 : key;
            const bf16_t* kr = kb + (size_t)key_eff * 2048 + (size_t)b * 512 + hoffg;
            bf16x8 bk0 = *(const bf16x8*)(kr + quad * 8);
            bf16x8 bk1 = *(const bf16x8*)(kr + 32 + quad * 8);
            f32x4 acc = {};
            acc = __builtin_amdgcn_mfma_f32_16x16x32_bf16(aq0, bk0, acc, 0, 0, 0);
            acc = __builtin_amdgcn_mfma_f32_16x16x32_bf16(aq1, bk1, acc, 0, 0, 0);
#pragma unroll
            for (int r = 0; r < 4; r++) {
                int ql = quad * 4 + r;
                bool valid = (key >= sq[r]) && (key < eq[r]);
                float p = valid ? __expf(0.125f * acc[r]) : 0.0f;
                l[r] += p;
                if (ql < 8) Ps[w][ql][cb + t8 * 16 + row16] = __float2bfloat16(p);
            }
        }
    }
    // reduce l over the 16 key-lanes of each quad group
#pragma unroll
    for (int off = 1; off < 16; off <<= 1) {
#pragma unroll
        for (int r = 0; r < 4; r++) l[r] += __shfl_xor(l[r], off, 64);
    }
    float linv[4];
#pragma unroll
    for (int r = 0; r < 4; r++) linv[r] = 1.0f / l[r];
    if (row16 == 0) {
#pragma unroll
        for (int r = 0; r < 4; r++) {
            int ql = quad * 4 + r;
            if (ql < 8) Ls[w][ql] = linv[r];
        }
    }
    __syncthreads();

    // ---- attn_out: atomic add of (1/8) * sum_h P_h * linv_h over the window ----
    {
        int qq = tid >> 5;              // 0..7
        int ln2 = tid & 31;
        float ls0 = Ls[0][qq] * 0.125f, ls1 = Ls[1][qq] * 0.125f;
        float ls2 = Ls[2][qq] * 0.125f, ls3 = Ls[3][qq] * 0.125f;
        float* base = attn_out + ((size_t)b * LQ + q0 + qq) * LK + us;
        const int cmax = LK - us;       // guard: never write past the row end
        for (int col = ln2; col < 896; col += 32) {
            if (col < cmax) {
                float s = ls0 * tofl(Ps[0][qq][col]) + ls1 * tofl(Ps[1][qq][col]) +
                          ls2 * tofl(Ps[2][qq][col]) + ls3 * tofl(Ps[3][qq][col]);
                atomicAdd(base + col, s);
            }
        }
    }

    // ---- PV on unnormalized P; scale by linv in epilogue ----
    f32x4 o[4] = {};
    for (int c = 0; c < 7; c++) {
        const int cb = c * 128;
#pragma unroll
        for (int kt2 = 0; kt2 < 4; kt2++) {
            const bf16_t* ap_src = (row16 < 8) ? &Ps[w][row16][cb + kt2 * 32 + quad * 8]
                                               : &Zrow[0];
            bf16x8 ap = *(const bf16x8*)ap_src;
#pragma unroll
            for (int nt = 0; nt < 4; nt++) {
                const bf16_t* vr = vT + ((size_t)b * 512 + hoffg + nt * 16 + row16) * 4096
                                   + us + cb + kt2 * 32 + quad * 8;
                bf16x8 bv = *(const bf16x8*)vr;
                o[nt] = __builtin_amdgcn_mfma_f32_16x16x32_bf16(ap, bv, o[nt], 0, 0, 0);
            }
        }
    }
#pragma unroll
    for (int nt = 0; nt < 4; nt++) {
#pragma unroll
        for (int r = 0; r < 4; r++) {
            int ql = quad * 4 + r;
            if (ql < 8) {
                ctx[((size_t)(q0 + ql) * 4 + b) * 512 + hoffg + nt * 16 + row16] =
                    __float2bfloat16(o[nt][r] * linv[r]);
            }
        }
    }
}

extern "C" void kernel_launch(void* const* d_in, const int* in_sizes, int n_in,
                              void* d_out, int out_size, void* d_ws, size_t ws_size,
                              hipStream_t stream) {
    const float* tgt    = (const float*)d_in[0];
    const float* memory = (const float*)d_in[1];
    const float* Wq = (const float*)d_in[2];
    const float* bq = (const float*)d_in[3];
    const float* Wk = (const float*)d_in[4];
    const float* bk = (const float*)d_in[5];
    const float* Wv = (const float*)d_in[6];
    const float* bv = (const float*)d_in[7];
    const float* Wo = (const float*)d_in[8];
    const float* bo = (const float*)d_in[9];
    const float* W1 = (const float*)d_in[10];
    const float* b1 = (const float*)d_in[11];
    const float* W2 = (const float*)d_in[12];
    const float* b2 = (const float*)d_in[13];
    const float* ln1w = (const float*)d_in[14];
    const float* ln1b = (const float*)d_in[15];
    const float* ln2w = (const float*)d_in[16];
    const float* ln2b = (const float*)d_in[17];
    const float* ln3w = (const float*)d_in[18];
    const float* ln3b = (const float*)d_in[19];
    const float* ln4w = (const float*)d_in[20];
    const float* ln4b = (const float*)d_in[21];

    const size_t M1 = (size_t)LQ * BATCH;      // 2048
    const size_t M2 = (size_t)LK * BATCH;      // 16384
    const size_t SZ1 = M1 * DMODEL;

    char* wsb = (char*)d_ws;
    const size_t MB = 1 << 20;
    bf16_t* m_buf   = (bf16_t*)(wsb + 0 * MB);
    bf16_t* vT_buf  = (bf16_t*)(wsb + 0 * MB);
    bf16_t* h_buf   = (bf16_t*)(wsb + 0 * MB);
    float*  xln_f   = (float*)(wsb + 8 * MB);
    float*  x2_buf  = (float*)(wsb + 12 * MB);
    bf16_t* k_buf   = (bf16_t*)(wsb + 16 * MB);
    bf16_t* v_buf   = (bf16_t*)(wsb + 32 * MB);
    bf16_t* t_bf    = (bf16_t*)(wsb + 48 * MB);
    bf16_t* xln_bf  = (bf16_t*)(wsb + 48 * MB);
    float*  t_f32   = (float*)(wsb + 50 * MB);
    bf16_t* q_bf    = (bf16_t*)(wsb + 54 * MB);
    float*  xres    = (float*)(wsb + 54 * MB);
    bf16_t* ctx_buf = (bf16_t*)(wsb + 58 * MB);
    bf16_t* wqkvo   = (bf16_t*)(wsb + 60 * MB);
    bf16_t* wff     = (bf16_t*)(wsb + 62 * MB);

    bf16_t* Wq_bf = wqkvo;
    bf16_t* Wk_bf = wqkvo + 262144;
    bf16_t* Wv_bf = wqkvo + 2 * 262144;
    bf16_t* Wo_bf = wqkvo + 3 * 262144;

    float* out_x    = (float*)d_out;
    float* out_attn = out_x + SZ1;

    conv4_kernel<<<dim3(1024), dim3(256), 0, stream>>>(Wq, Wk, Wv, Wo, wqkvo);
    zero_attn<<<dim3(8192), dim3(256), 0, stream>>>(out_attn);

    ln_kernel<bf16_t, true><<<dim3(M1), dim3(256), 0, stream>>>(tgt, ln1w, ln1b, t_bf, t_f32);
    ln_kernel<bf16_t, false><<<dim3(M2), dim3(256), 0, stream>>>(memory, ln2w, ln2b, m_buf, nullptr);

    gemm_mfma<bf16_t, false, false><<<dim3(DMODEL / GBN, M1 / GBM), dim3(256), 0, stream>>>(
        t_bf, Wq_bf, bq, nullptr, q_bf, M1, DMODEL, DMODEL);
    gemm_mfma<bf16_t, false, false><<<dim3(DMODEL / GBN, M2 / GBM), dim3(256), 0, stream>>>(
        m_buf, Wk_bf, bk, nullptr, k_buf, M2, DMODEL, DMODEL);
    gemm_mfma<bf16_t, false, false><<<dim3(DMODEL / GBN, M2 / GBM), dim3(256), 0, stream>>>(
        m_buf, Wv_bf, bv, nullptr, v_buf, M2, DMODEL, DMODEL);

    // V transpose to [b][d][key] (m_buf dead -> vT region)
    transpose_kv<<<dim3(64, 8, 4), dim3(256), 0, stream>>>(v_buf, vT_buf);

    attn_mfma<<<dim3(512), dim3(256), 0, stream>>>(q_bf, k_buf, vT_buf, ctx_buf, out_attn);

    gemm_mfma<float, false, true><<<dim3(DMODEL / GBN, M1 / GBM), dim3(256), 0, stream>>>(
        ctx_buf, Wo_bf, bo, t_f32, xres, M1, DMODEL, DMODEL);

    ln_kernel<bf16_t, true><<<dim3(M1), dim3(256), 0, stream>>>(xres, ln3w, ln3b, xln_bf, xln_f);

    convw_kernel<<<dim3(1024), dim3(256), 0, stream>>>(W1, wff, DFF * DMODEL);
    gemm_mfma<bf16_t, true, false><<<dim3(DFF / GBN, M1 / GBM), dim3(256), 0, stream>>>(
        xln_bf, wff, b1, nullptr, h_buf, M1, DFF, DMODEL);

    convw_kernel<<<dim3(1024), dim3(256), 0, stream>>>(W2, wff, DMODEL * DFF);
    gemm_mfma<float, false, true><<<dim3(DMODEL / GBN, M1 / GBM), dim3(256), 0, stream>>>(
        h_buf, wff, b2, xln_f, x2_buf, M1, DMODEL, DFF);

    ln_kernel<float, false><<<dim3(M1), dim3(256), 0, stream>>>(x2_buf, ln4w, ln4b, out_x, nullptr);
}